// Round 1
// baseline (1674.291 us; speedup 1.0000x reference)
//
#include <hip/hip_runtime.h>
#include <math.h>

// ---------------------------------------------------------------------------
// GAT 3-layer forward, MI355X. Round 1: correct f32-compute baseline,
// bf16 intermediate storage, CSR-by-dst edge aggregation (no atomics in the
// hot path). GEMMs are plain VALU f32 (MFMA comes in round 2).
// ---------------------------------------------------------------------------

#define NEG_ATT 0.2f
#define NEG_ACT 0.01f

__device__ __forceinline__ float bf2f(unsigned short u) {
  union { unsigned int i; float f; } c; c.i = ((unsigned int)u) << 16; return c.f;
}
__device__ __forceinline__ unsigned short f2bf(float f) {
  union { float f; unsigned int i; } c; c.f = f;
  unsigned int r = c.i + 0x7FFFu + ((c.i >> 16) & 1u);
  return (unsigned short)(r >> 16);
}

// ---------------------------------------------------------------------------
// CSR build: histogram -> exclusive scan -> scatter (src sorted by dst)
// ---------------------------------------------------------------------------
__global__ void hist_kernel(const int* __restrict__ edge_dst,
                            int* __restrict__ cnt, int E, int N) {
  int e = blockIdx.x * 256 + threadIdx.x;
  if (e >= E + N) return;
  int dn = (e < E) ? edge_dst[e] : (e - E);   // self-loops appended
  atomicAdd(&cnt[dn], 1);
}

__global__ __launch_bounds__(1024) void scan_kernel(const int* __restrict__ cnt,
    int* __restrict__ row_ptr, int* __restrict__ cur, int N) {
  __shared__ int sbuf[1024];
  int tid = threadIdx.x;
  int CH = (N + 1023) / 1024;
  int beg = tid * CH;
  int end = beg + CH; if (end > N) end = N;
  int lsum = 0;
  for (int i = beg; i < end; i++) lsum += cnt[i];
  sbuf[tid] = lsum;
  __syncthreads();
  for (int off = 1; off < 1024; off <<= 1) {
    int v = (tid >= off) ? sbuf[tid - off] : 0;
    __syncthreads();
    sbuf[tid] += v;
    __syncthreads();
  }
  int run = sbuf[tid] - lsum;  // exclusive prefix
  for (int i = beg; i < end; i++) {
    row_ptr[i] = run; cur[i] = run;
    run += cnt[i];
  }
  if (tid == 1023) row_ptr[N] = sbuf[1023];
}

__global__ void scatter_kernel(const int* __restrict__ edge_src,
                               const int* __restrict__ edge_dst,
                               int* __restrict__ cur,
                               int* __restrict__ src_sorted, int E, int N) {
  int e = blockIdx.x * 256 + threadIdx.x;
  if (e >= E + N) return;
  int sn, dn;
  if (e < E) { sn = edge_src[e]; dn = edge_dst[e]; }
  else       { sn = dn = e - E; }
  int pos = atomicAdd(&cur[dn], 1);
  src_sorted[pos] = sn;
}

// ---------------------------------------------------------------------------
// GEMM: C[m][n] = sum_k A[m][k] * W[n][k]   (A row-major [M,K], W row-major
// [N,K]); A is f32 (layer 1 input) or bf16 (activations); C stored bf16.
// 256 threads, BMxBN tile, TMxTN micro-tile, LDS transposed tiles.
// ---------------------------------------------------------------------------
__device__ __forceinline__ float4 loadA4(const float* p) {
  return *reinterpret_cast<const float4*>(p);
}
__device__ __forceinline__ float4 loadA4(const unsigned short* p) {
  ushort4 u = *reinterpret_cast<const ushort4*>(p);
  return make_float4(bf2f(u.x), bf2f(u.y), bf2f(u.z), bf2f(u.w));
}

template <typename TA, int BM, int BN, int BK, int TM, int TN>
__global__ __launch_bounds__(256) void gemm_tn(
    const TA* __restrict__ A, const float* __restrict__ W,
    unsigned short* __restrict__ C, int M, int N, int K) {
  __shared__ float As[BK][BM + 4];
  __shared__ float Bs[BK][BN + 4];
  const int tid = threadIdx.x;
  const int bm = blockIdx.x * BM;
  const int bn = blockIdx.y * BN;
  constexpr int TX = BN / TN;               // threads along n
  const int tn0 = (tid % TX) * TN;
  const int tm0 = (tid / TX) * TM;
  float acc[TM][TN];
#pragma unroll
  for (int i = 0; i < TM; i++)
#pragma unroll
    for (int j = 0; j < TN; j++) acc[i][j] = 0.f;

  for (int k0 = 0; k0 < K; k0 += BK) {
    constexpr int ACH = BM * BK / 4;
    for (int i = tid; i < ACH; i += 256) {
      int row = i / (BK / 4);
      int kc = (i % (BK / 4)) * 4;
      float4 v = make_float4(0.f, 0.f, 0.f, 0.f);
      int gr = bm + row;
      if (gr < M) v = loadA4(A + (size_t)gr * K + k0 + kc);
      As[kc + 0][row] = v.x; As[kc + 1][row] = v.y;
      As[kc + 2][row] = v.z; As[kc + 3][row] = v.w;
    }
    constexpr int BCH = BN * BK / 4;
    for (int i = tid; i < BCH; i += 256) {
      int row = i / (BK / 4);
      int kc = (i % (BK / 4)) * 4;
      float4 v = *reinterpret_cast<const float4*>(W + (size_t)(bn + row) * K + k0 + kc);
      Bs[kc + 0][row] = v.x; Bs[kc + 1][row] = v.y;
      Bs[kc + 2][row] = v.z; Bs[kc + 3][row] = v.w;
    }
    __syncthreads();
#pragma unroll
    for (int k = 0; k < BK; k++) {
      float a[TM], b[TN];
#pragma unroll
      for (int i = 0; i < TM; i++) a[i] = As[k][tm0 + i];
#pragma unroll
      for (int j = 0; j < TN; j++) b[j] = Bs[k][tn0 + j];
#pragma unroll
      for (int i = 0; i < TM; i++)
#pragma unroll
        for (int j = 0; j < TN; j++) acc[i][j] = fmaf(a[i], b[j], acc[i][j]);
    }
    __syncthreads();
  }
#pragma unroll
  for (int i = 0; i < TM; i++) {
    int m = bm + tm0 + i;
    if (m >= M) continue;
#pragma unroll
    for (int j = 0; j < TN; j++)
      C[(size_t)m * N + bn + tn0 + j] = f2bf(acc[i][j]);
  }
}

// ---------------------------------------------------------------------------
// s[n][h] = <h_row, a_src[h]>, d[n][h] = <h_row, a_dst[h]>   (H=4 layers 1&2)
// one block per node, one wave per head
// ---------------------------------------------------------------------------
template <int C>
__global__ __launch_bounds__(256) void sd_kernel(
    const unsigned short* __restrict__ h, const float* __restrict__ a_src,
    const float* __restrict__ a_dst, float* __restrict__ s,
    float* __restrict__ d, int N) {
  constexpr int H = 4;
  constexpr int VEC = C / 64;
  int n = blockIdx.x;
  int head = threadIdx.x >> 6;
  int lane = threadIdx.x & 63;
  const unsigned short* row = h + (size_t)n * (H * C) + head * C + lane * VEC;
  float ss = 0.f, dd = 0.f;
  if constexpr (VEC == 4) {
    ushort4 u = *reinterpret_cast<const ushort4*>(row);
    float4 a = *reinterpret_cast<const float4*>(a_src + head * C + lane * 4);
    float4 b = *reinterpret_cast<const float4*>(a_dst + head * C + lane * 4);
    ss = bf2f(u.x) * a.x + bf2f(u.y) * a.y + bf2f(u.z) * a.z + bf2f(u.w) * a.w;
    dd = bf2f(u.x) * b.x + bf2f(u.y) * b.y + bf2f(u.z) * b.z + bf2f(u.w) * b.w;
  } else {
    ushort2 u = *reinterpret_cast<const ushort2*>(row);
    float2 a = *reinterpret_cast<const float2*>(a_src + head * C + lane * 2);
    float2 b = *reinterpret_cast<const float2*>(a_dst + head * C + lane * 2);
    ss = bf2f(u.x) * a.x + bf2f(u.y) * a.y;
    dd = bf2f(u.x) * b.x + bf2f(u.y) * b.y;
  }
#pragma unroll
  for (int o = 32; o; o >>= 1) { ss += __shfl_down(ss, o); dd += __shfl_down(dd, o); }
  if (lane == 0) { s[(size_t)n * H + head] = ss; d[(size_t)n * H + head] = dd; }
}

// layer 3: H=1, C=32; 8 nodes per block, 32 lanes per node
__global__ __launch_bounds__(256) void sd32_kernel(
    const unsigned short* __restrict__ h, const float* __restrict__ a_src,
    const float* __restrict__ a_dst, float* __restrict__ s,
    float* __restrict__ d, int N) {
  int idx = blockIdx.x * 256 + threadIdx.x;
  int n = idx >> 5, c = idx & 31;
  if (n >= N) return;
  float v = bf2f(h[(size_t)n * 32 + c]);
  float ss = v * a_src[c], dd = v * a_dst[c];
#pragma unroll
  for (int o = 16; o; o >>= 1) { ss += __shfl_xor(ss, o, 32); dd += __shfl_xor(dd, o, 32); }
  if (c == 0) { s[n] = ss; d[n] = dd; }
}

// ---------------------------------------------------------------------------
// Per-(dst,head) softmax stats over incoming edges: p (unnormalized, max-
// shifted) stored per sorted edge, 1/(denom+1e-16) per (node,head).
// ---------------------------------------------------------------------------
__global__ void stats_kernel(const int* __restrict__ row_ptr,
    const int* __restrict__ src_sorted, const float* __restrict__ s,
    const float* __restrict__ d, float* __restrict__ p_sorted,
    float* __restrict__ inv_den, int N, int H) {
  int idx = blockIdx.x * blockDim.x + threadIdx.x;
  if (idx >= N * H) return;
  int n = idx / H, h = idx % H;
  int beg = row_ptr[n], end = row_ptr[n + 1];
  float dn = d[idx];
  float mx = -1e30f;
  for (int j = beg; j < end; j++) {
    float v = s[(size_t)src_sorted[j] * H + h] + dn;
    v = v > 0.f ? v : NEG_ATT * v;
    mx = fmaxf(mx, v);
  }
  float den = 0.f;
  for (int j = beg; j < end; j++) {
    float v = s[(size_t)src_sorted[j] * H + h] + dn;
    v = v > 0.f ? v : NEG_ATT * v;
    float p = __expf(v - mx);
    p_sorted[(size_t)j * H + h] = p;
    den += p;
  }
  inv_den[idx] = 1.0f / (den + 1e-16f);
}

// ---------------------------------------------------------------------------
// Aggregation out[n][:] = inv_den * sum_j p_j * h[src_j][:]  + bias,
// then LayerNorm over HC channels, then leaky_relu(0.01); store bf16.
// One block (256 thr) per node; VEC = HC/256 channels per thread.
// ---------------------------------------------------------------------------
template <int HC, int H, int VEC>
__global__ __launch_bounds__(256) void agg_ln_kernel(
    const int* __restrict__ row_ptr, const int* __restrict__ src_sorted,
    const float* __restrict__ p_sorted, const float* __restrict__ inv_den,
    const unsigned short* __restrict__ hbuf, const float* __restrict__ bias,
    const float* __restrict__ ln_g, const float* __restrict__ ln_b,
    unsigned short* __restrict__ outb, int N) {
  constexpr int C = HC / H;
  int n = blockIdx.x;
  int tid = threadIdx.x;
  int c0 = tid * VEC;
  int head = c0 / C;
  int beg = row_ptr[n], end = row_ptr[n + 1];
  float acc[VEC];
#pragma unroll
  for (int i = 0; i < VEC; i++) acc[i] = 0.f;
  for (int j = beg; j < end; j++) {
    int srcn = src_sorted[j];
    float p = p_sorted[(size_t)j * H + head];
    const unsigned short* hp = hbuf + (size_t)srcn * HC + c0;
    if constexpr (VEC == 4) {
      ushort4 u = *reinterpret_cast<const ushort4*>(hp);
      acc[0] = fmaf(p, bf2f(u.x), acc[0]);
      acc[1] = fmaf(p, bf2f(u.y), acc[1]);
      acc[2] = fmaf(p, bf2f(u.z), acc[2]);
      acc[3] = fmaf(p, bf2f(u.w), acc[3]);
    } else {
      ushort2 u = *reinterpret_cast<const ushort2*>(hp);
      acc[0] = fmaf(p, bf2f(u.x), acc[0]);
      acc[1] = fmaf(p, bf2f(u.y), acc[1]);
    }
  }
  float scale = inv_den[(size_t)n * H + head];
  float v[VEC]; float s1 = 0.f, s2 = 0.f;
#pragma unroll
  for (int i = 0; i < VEC; i++) {
    v[i] = acc[i] * scale + bias[c0 + i];
    s1 += v[i]; s2 += v[i] * v[i];
  }
#pragma unroll
  for (int o = 32; o; o >>= 1) { s1 += __shfl_down(s1, o); s2 += __shfl_down(s2, o); }
  __shared__ float r1[4], r2[4];
  int wave = tid >> 6, lane = tid & 63;
  if (lane == 0) { r1[wave] = s1; r2[wave] = s2; }
  __syncthreads();
  float t1 = r1[0] + r1[1] + r1[2] + r1[3];
  float t2 = r2[0] + r2[1] + r2[2] + r2[3];
  float mean = t1 * (1.0f / HC);
  float var = t2 * (1.0f / HC) - mean * mean;
  float rstd = rsqrtf(var + 1e-5f);
#pragma unroll
  for (int i = 0; i < VEC; i++) {
    float y = (v[i] - mean) * rstd * ln_g[c0 + i] + ln_b[c0 + i];
    y = y > 0.f ? y : NEG_ACT * y;
    outb[(size_t)n * HC + c0 + i] = f2bf(y);
  }
}

// ---------------------------------------------------------------------------
// Layer-3 aggregation + bias + LN(32) + log_softmax(32) -> f32 output.
// 32 lanes per node, 8 nodes per block.
// ---------------------------------------------------------------------------
__global__ __launch_bounds__(256) void final_kernel(
    const int* __restrict__ row_ptr, const int* __restrict__ src_sorted,
    const float* __restrict__ p_sorted, const float* __restrict__ inv_den,
    const unsigned short* __restrict__ h3, const float* __restrict__ b3,
    const float* __restrict__ g3, const float* __restrict__ bb3,
    float* __restrict__ out, int N) {
  int idx = blockIdx.x * 256 + threadIdx.x;
  int n = idx >> 5, c = idx & 31;
  if (n >= N) return;
  int beg = row_ptr[n], end = row_ptr[n + 1];
  float acc = 0.f;
  for (int j = beg; j < end; j++)
    acc = fmaf(p_sorted[j], bf2f(h3[(size_t)src_sorted[j] * 32 + c]), acc);
  float v = acc * inv_den[n] + b3[c];
  float s1 = v, s2 = v * v;
#pragma unroll
  for (int o = 16; o; o >>= 1) { s1 += __shfl_xor(s1, o, 32); s2 += __shfl_xor(s2, o, 32); }
  float mean = s1 * (1.f / 32.f), var = s2 * (1.f / 32.f) - mean * mean;
  float y = (v - mean) * rsqrtf(var + 1e-5f) * g3[c] + bb3[c];
  float mx = y;
#pragma unroll
  for (int o = 16; o; o >>= 1) mx = fmaxf(mx, __shfl_xor(mx, o, 32));
  float ex = __expf(y - mx), se = ex;
#pragma unroll
  for (int o = 16; o; o >>= 1) se += __shfl_xor(se, o, 32);
  out[(size_t)n * 32 + c] = y - mx - __logf(se);
}

// ---------------------------------------------------------------------------
extern "C" void kernel_launch(void* const* d_in, const int* in_sizes, int n_in,
                              void* d_out, int out_size, void* d_ws,
                              size_t ws_size, hipStream_t stream) {
  const float* x   = (const float*)d_in[0];
  const int* esrc  = (const int*)d_in[1];
  const int* edst  = (const int*)d_in[2];
  const float* W1  = (const float*)d_in[3];
  const float* as1 = (const float*)d_in[4];
  const float* ad1 = (const float*)d_in[5];
  const float* b1  = (const float*)d_in[6];
  const float* g1  = (const float*)d_in[7];
  const float* bb1 = (const float*)d_in[8];
  const float* W2  = (const float*)d_in[9];
  const float* as2 = (const float*)d_in[10];
  const float* ad2 = (const float*)d_in[11];
  const float* b2  = (const float*)d_in[12];
  const float* g2  = (const float*)d_in[13];
  const float* bb2 = (const float*)d_in[14];
  const float* W3  = (const float*)d_in[15];
  const float* as3 = (const float*)d_in[16];
  const float* ad3 = (const float*)d_in[17];
  const float* b3  = (const float*)d_in[18];
  const float* g3  = (const float*)d_in[19];
  const float* bb3 = (const float*)d_in[20];
  float* out = (float*)d_out;

  const int N = in_sizes[0] / 256;   // 50000
  const int E = in_sizes[1];         // 400000
  const int Etot = E + N;

  char* ws = (char*)d_ws;
  size_t off = 0;
  auto alloc = [&](size_t bytes) -> char* {
    char* p = ws + off;
    off += (bytes + 255) & ~(size_t)255;
    return p;
  };
  int* cnt        = (int*)alloc((size_t)(N + 1) * 4);
  int* cur        = (int*)alloc((size_t)(N + 1) * 4);
  int* row_ptr    = (int*)alloc((size_t)(N + 1) * 4);
  int* src_sorted = (int*)alloc((size_t)Etot * 4);
  float* s1    = (float*)alloc((size_t)N * 4 * 4);
  float* d1    = (float*)alloc((size_t)N * 4 * 4);
  float* invd1 = (float*)alloc((size_t)N * 4 * 4);
  float* p1    = (float*)alloc((size_t)Etot * 4 * 4);
  float* s2    = (float*)alloc((size_t)N * 4 * 4);
  float* d2    = (float*)alloc((size_t)N * 4 * 4);
  float* invd2 = (float*)alloc((size_t)N * 4 * 4);
  float* p2    = (float*)alloc((size_t)Etot * 4 * 4);
  float* s3    = (float*)alloc((size_t)N * 4);
  float* d3    = (float*)alloc((size_t)N * 4);
  float* invd3 = (float*)alloc((size_t)N * 4);
  float* p3    = (float*)alloc((size_t)Etot * 4);
  unsigned short* h1   = (unsigned short*)alloc((size_t)N * 1024 * 2);
  unsigned short* act1 = (unsigned short*)alloc((size_t)N * 1024 * 2);
  // buffer reuse: h2 overlays h1 (h1 dead after agg1); act2 overlays h1's
  // second half; h3 overlays act1 (act1 dead after GEMM2).
  unsigned short* h2   = h1;
  unsigned short* act2 = (unsigned short*)((char*)h1 + (size_t)N * 512 * 2);
  unsigned short* h3   = act1;

  // ---- CSR by dst (rebuilt every call; d_ws is re-poisoned) ----
  hipMemsetAsync(cnt, 0, (size_t)(N + 1) * 4, stream);
  int eb = (Etot + 255) / 256;
  hist_kernel<<<eb, 256, 0, stream>>>(edst, cnt, E, N);
  scan_kernel<<<1, 1024, 0, stream>>>(cnt, row_ptr, cur, N);
  scatter_kernel<<<eb, 256, 0, stream>>>(esrc, edst, cur, src_sorted, E, N);

  int mb = (N + 127) / 128;
  // ---- layer 1 ----
  gemm_tn<float, 128, 128, 16, 8, 8>
      <<<dim3(mb, 1024 / 128), 256, 0, stream>>>(x, W1, h1, N, 1024, 256);
  sd_kernel<256><<<N, 256, 0, stream>>>(h1, as1, ad1, s1, d1, N);
  stats_kernel<<<(N * 4 + 255) / 256, 256, 0, stream>>>(row_ptr, src_sorted,
                                                        s1, d1, p1, invd1, N, 4);
  agg_ln_kernel<1024, 4, 4><<<N, 256, 0, stream>>>(row_ptr, src_sorted, p1,
      invd1, h1, b1, g1, bb1, act1, N);
  // ---- layer 2 ----
  gemm_tn<unsigned short, 128, 128, 16, 8, 8>
      <<<dim3(mb, 512 / 128), 256, 0, stream>>>(act1, W2, h2, N, 512, 1024);
  sd_kernel<128><<<N, 256, 0, stream>>>(h2, as2, ad2, s2, d2, N);
  stats_kernel<<<(N * 4 + 255) / 256, 256, 0, stream>>>(row_ptr, src_sorted,
                                                        s2, d2, p2, invd2, N, 4);
  agg_ln_kernel<512, 4, 2><<<N, 256, 0, stream>>>(row_ptr, src_sorted, p2,
      invd2, h2, b2, g2, bb2, act2, N);
  // ---- layer 3 ----
  gemm_tn<unsigned short, 128, 32, 16, 8, 2>
      <<<dim3(mb, 1), 256, 0, stream>>>(act2, W3, h3, N, 32, 512);
  sd32_kernel<<<(N * 32 + 255) / 256, 256, 0, stream>>>(h3, as3, ad3, s3, d3, N);
  stats_kernel<<<(N + 255) / 256, 256, 0, stream>>>(row_ptr, src_sorted,
                                                    s3, d3, p3, invd3, N, 1);
  final_kernel<<<(N * 32 + 255) / 256, 256, 0, stream>>>(row_ptr, src_sorted,
      p3, invd3, h3, b3, g3, bb3, out, N);
}

// Round 2
// 847.535 us; speedup vs baseline: 1.9755x; 1.9755x over previous
//
#include <hip/hip_runtime.h>
#include <math.h>

// ---------------------------------------------------------------------------
// GAT 3-layer forward, MI355X. Round 2: MFMA bf16 GEMMs (m97-style:
// global_load_lds width-16 staging, XOR-swizzled LDS, 16x16x32 bf16 MFMA).
// Edge pipeline (CSR build, segment softmax, gather-aggregate+LN) unchanged.
// ---------------------------------------------------------------------------

#define NEG_ATT 0.2f
#define NEG_ACT 0.01f

typedef __attribute__((ext_vector_type(8))) short bf16x8;
typedef __attribute__((ext_vector_type(4))) float f32x4;

__device__ __forceinline__ float bf2f(unsigned short u) {
  union { unsigned int i; float f; } c; c.i = ((unsigned int)u) << 16; return c.f;
}
__device__ __forceinline__ unsigned short f2bf(float f) {
  union { float f; unsigned int i; } c; c.f = f;
  unsigned int r = c.i + 0x7FFFu + ((c.i >> 16) & 1u);
  return (unsigned short)(r >> 16);
}

// ---------------------------------------------------------------------------
// f32 -> bf16 bulk convert (n divisible by 8)
// ---------------------------------------------------------------------------
__global__ void cvt_kernel(const float* __restrict__ in,
                           unsigned short* __restrict__ out, int n8) {
  int i = blockIdx.x * 256 + threadIdx.x;
  if (i >= n8) return;
  float4 v0 = reinterpret_cast<const float4*>(in)[i * 2];
  float4 v1 = reinterpret_cast<const float4*>(in)[i * 2 + 1];
  ushort4 o0 = make_ushort4(f2bf(v0.x), f2bf(v0.y), f2bf(v0.z), f2bf(v0.w));
  ushort4 o1 = make_ushort4(f2bf(v1.x), f2bf(v1.y), f2bf(v1.z), f2bf(v1.w));
  reinterpret_cast<ushort4*>(out)[i * 2] = o0;
  reinterpret_cast<ushort4*>(out)[i * 2 + 1] = o1;
}

// ---------------------------------------------------------------------------
// CSR build: histogram -> exclusive scan -> scatter (src sorted by dst)
// ---------------------------------------------------------------------------
__global__ void hist_kernel(const int* __restrict__ edge_dst,
                            int* __restrict__ cnt, int E, int N) {
  int e = blockIdx.x * 256 + threadIdx.x;
  if (e >= E + N) return;
  int dn = (e < E) ? edge_dst[e] : (e - E);   // self-loops appended
  atomicAdd(&cnt[dn], 1);
}

__global__ __launch_bounds__(1024) void scan_kernel(const int* __restrict__ cnt,
    int* __restrict__ row_ptr, int* __restrict__ cur, int N) {
  __shared__ int sbuf[1024];
  int tid = threadIdx.x;
  int CH = (N + 1023) / 1024;
  int beg = tid * CH;
  int end = beg + CH; if (end > N) end = N;
  int lsum = 0;
  for (int i = beg; i < end; i++) lsum += cnt[i];
  sbuf[tid] = lsum;
  __syncthreads();
  for (int off = 1; off < 1024; off <<= 1) {
    int v = (tid >= off) ? sbuf[tid - off] : 0;
    __syncthreads();
    sbuf[tid] += v;
    __syncthreads();
  }
  int run = sbuf[tid] - lsum;  // exclusive prefix
  for (int i = beg; i < end; i++) {
    row_ptr[i] = run; cur[i] = run;
    run += cnt[i];
  }
  if (tid == 1023) row_ptr[N] = sbuf[1023];
}

__global__ void scatter_kernel(const int* __restrict__ edge_src,
                               const int* __restrict__ edge_dst,
                               int* __restrict__ cur,
                               int* __restrict__ src_sorted, int E, int N) {
  int e = blockIdx.x * 256 + threadIdx.x;
  if (e >= E + N) return;
  int sn, dn;
  if (e < E) { sn = edge_src[e]; dn = edge_dst[e]; }
  else       { sn = dn = e - E; }
  int pos = atomicAdd(&cur[dn], 1);
  src_sorted[pos] = sn;
}

// ---------------------------------------------------------------------------
// MFMA bf16 GEMM: C[m][n] = sum_k A[m][k] * B[n][k]   (A [M,K], B [N,K] bf16
// row-major, C [M,N] bf16). 256 threads = 4 waves, wave grid WMxWN, each wave
// FMx FN 16x16 fragments. BK=64. global_load_lds staging with XOR-swizzled
// LDS layout (swizzle applied to global SOURCE address + ds_read address;
// LDS destination stays linear as global_load_lds requires).
// Swizzle: phys_byte = byte ^ (((byte>>7)&7)<<4) -- rows 0..7 of a 128B-wide
// tile spread across all 32 banks; residual 2-way conflict is free.
// ---------------------------------------------------------------------------
#define GLOBAL_AS __attribute__((address_space(1)))
#define LDS_AS __attribute__((address_space(3)))

__device__ __forceinline__ void gload_lds16(const void* g, void* l) {
  __builtin_amdgcn_global_load_lds((const GLOBAL_AS unsigned int*)g,
                                   (LDS_AS unsigned int*)l, 16, 0, 0);
}

template <int BM, int BN, int WM, int WN>
__global__ __launch_bounds__(256) void gemm_mfma(
    const unsigned short* __restrict__ A, const unsigned short* __restrict__ B,
    unsigned short* __restrict__ C, int M, int N, int K) {
  constexpr int BK = 64;
  constexpr int FM = BM / (WM * 16);
  constexpr int FN = BN / (WN * 16);
  __shared__ unsigned short As[BM * BK];
  __shared__ unsigned short Bs[BN * BK];
  const int tid = threadIdx.x;
  const int w = tid >> 6, lane = tid & 63;
  const int wm = w / WN, wn = w % WN;
  const int bm = blockIdx.x * BM, bn = blockIdx.y * BN;
  const int l15 = lane & 15, l4 = lane >> 4;

  f32x4 acc[FM][FN] = {};

  constexpr int CHA = BM * BK / 8;   // 16B chunks in A tile
  constexpr int CHB = BN * BK / 8;

  for (int k0 = 0; k0 < K; k0 += BK) {
    // ---- stage A tile: chunk c lands at linear LDS chunk c; fetch the
    //      global element that logically belongs at swizzled(c).
#pragma unroll
    for (int j = 0; j < CHA / 256; j++) {
      int c = j * 256 + tid;
      int cl = c ^ ((c >> 3) & 7);
      int row = cl >> 3;
      int kk = (cl & 7) * 8;
      int gr = bm + row; if (gr > M - 1) gr = M - 1;
      gload_lds16(A + (size_t)gr * K + k0 + kk,
                  As + (size_t)(j * 256 + (w << 6)) * 8);
    }
#pragma unroll
    for (int j = 0; j < CHB / 256; j++) {
      int c = j * 256 + tid;
      int cl = c ^ ((c >> 3) & 7);
      int row = cl >> 3;
      int kk = (cl & 7) * 8;
      gload_lds16(B + (size_t)(bn + row) * K + k0 + kk,
                  Bs + (size_t)(j * 256 + (w << 6)) * 8);
    }
    __syncthreads();
    // ---- compute: 2 sub-steps of K=32
#pragma unroll
    for (int ks = 0; ks < 2; ks++) {
      bf16x8 af[FM], bfr[FN];
#pragma unroll
      for (int i = 0; i < FM; i++) {
        int row = wm * (FM * 16) + i * 16 + l15;
        int byte = row * (BK * 2) + ks * 64 + l4 * 16;
        byte ^= ((byte >> 7) & 7) << 4;
        af[i] = *reinterpret_cast<const bf16x8*>((const char*)As + byte);
      }
#pragma unroll
      for (int i = 0; i < FN; i++) {
        int row = wn * (FN * 16) + i * 16 + l15;
        int byte = row * (BK * 2) + ks * 64 + l4 * 16;
        byte ^= ((byte >> 7) & 7) << 4;
        bfr[i] = *reinterpret_cast<const bf16x8*>((const char*)Bs + byte);
      }
#pragma unroll
      for (int i = 0; i < FM; i++)
#pragma unroll
        for (int jn = 0; jn < FN; jn++)
          acc[i][jn] = __builtin_amdgcn_mfma_f32_16x16x32_bf16(
              af[i], bfr[jn], acc[i][jn], 0, 0, 0);
    }
    __syncthreads();
  }
  // ---- epilogue: D col = lane&15, row = (lane>>4)*4 + reg (HW-verified)
#pragma unroll
  for (int i = 0; i < FM; i++) {
#pragma unroll
    for (int jn = 0; jn < FN; jn++) {
      int col = bn + wn * (FN * 16) + jn * 16 + l15;
#pragma unroll
      for (int r = 0; r < 4; r++) {
        int m = bm + wm * (FM * 16) + i * 16 + l4 * 4 + r;
        if (m < M) C[(size_t)m * N + col] = f2bf(acc[i][jn][r]);
      }
    }
  }
}

// ---------------------------------------------------------------------------
// s[n][h] = <h_row, a_src[h]>, d[n][h] = <h_row, a_dst[h]>   (H=4 layers 1&2)
// ---------------------------------------------------------------------------
template <int C>
__global__ __launch_bounds__(256) void sd_kernel(
    const unsigned short* __restrict__ h, const float* __restrict__ a_src,
    const float* __restrict__ a_dst, float* __restrict__ s,
    float* __restrict__ d, int N) {
  constexpr int H = 4;
  constexpr int VEC = C / 64;
  int n = blockIdx.x;
  int head = threadIdx.x >> 6;
  int lane = threadIdx.x & 63;
  const unsigned short* row = h + (size_t)n * (H * C) + head * C + lane * VEC;
  float ss = 0.f, dd = 0.f;
  if constexpr (VEC == 4) {
    ushort4 u = *reinterpret_cast<const ushort4*>(row);
    float4 a = *reinterpret_cast<const float4*>(a_src + head * C + lane * 4);
    float4 b = *reinterpret_cast<const float4*>(a_dst + head * C + lane * 4);
    ss = bf2f(u.x) * a.x + bf2f(u.y) * a.y + bf2f(u.z) * a.z + bf2f(u.w) * a.w;
    dd = bf2f(u.x) * b.x + bf2f(u.y) * b.y + bf2f(u.z) * b.z + bf2f(u.w) * b.w;
  } else {
    ushort2 u = *reinterpret_cast<const ushort2*>(row);
    float2 a = *reinterpret_cast<const float2*>(a_src + head * C + lane * 2);
    float2 b = *reinterpret_cast<const float2*>(a_dst + head * C + lane * 2);
    ss = bf2f(u.x) * a.x + bf2f(u.y) * a.y;
    dd = bf2f(u.x) * b.x + bf2f(u.y) * b.y;
  }
#pragma unroll
  for (int o = 32; o; o >>= 1) { ss += __shfl_down(ss, o); dd += __shfl_down(dd, o); }
  if (lane == 0) { s[(size_t)n * H + head] = ss; d[(size_t)n * H + head] = dd; }
}

// layer 3: H=1, C=32
__global__ __launch_bounds__(256) void sd32_kernel(
    const unsigned short* __restrict__ h, const float* __restrict__ a_src,
    const float* __restrict__ a_dst, float* __restrict__ s,
    float* __restrict__ d, int N) {
  int idx = blockIdx.x * 256 + threadIdx.x;
  int n = idx >> 5, c = idx & 31;
  if (n >= N) return;
  float v = bf2f(h[(size_t)n * 32 + c]);
  float ss = v * a_src[c], dd = v * a_dst[c];
#pragma unroll
  for (int o = 16; o; o >>= 1) { ss += __shfl_xor(ss, o, 32); dd += __shfl_xor(dd, o, 32); }
  if (c == 0) { s[n] = ss; d[n] = dd; }
}

// ---------------------------------------------------------------------------
// Per-(dst,head) softmax stats over incoming edges.
// ---------------------------------------------------------------------------
__global__ void stats_kernel(const int* __restrict__ row_ptr,
    const int* __restrict__ src_sorted, const float* __restrict__ s,
    const float* __restrict__ d, float* __restrict__ p_sorted,
    float* __restrict__ inv_den, int N, int H) {
  int idx = blockIdx.x * blockDim.x + threadIdx.x;
  if (idx >= N * H) return;
  int n = idx / H, h = idx % H;
  int beg = row_ptr[n], end = row_ptr[n + 1];
  float dn = d[idx];
  float mx = -1e30f;
  for (int j = beg; j < end; j++) {
    float v = s[(size_t)src_sorted[j] * H + h] + dn;
    v = v > 0.f ? v : NEG_ATT * v;
    mx = fmaxf(mx, v);
  }
  float den = 0.f;
  for (int j = beg; j < end; j++) {
    float v = s[(size_t)src_sorted[j] * H + h] + dn;
    v = v > 0.f ? v : NEG_ATT * v;
    float p = __expf(v - mx);
    p_sorted[(size_t)j * H + h] = p;
    den += p;
  }
  inv_den[idx] = 1.0f / (den + 1e-16f);
}

// ---------------------------------------------------------------------------
// Aggregation + bias + LayerNorm + leaky_relu(0.01); bf16 out.
// ---------------------------------------------------------------------------
template <int HC, int H, int VEC>
__global__ __launch_bounds__(256) void agg_ln_kernel(
    const int* __restrict__ row_ptr, const int* __restrict__ src_sorted,
    const float* __restrict__ p_sorted, const float* __restrict__ inv_den,
    const unsigned short* __restrict__ hbuf, const float* __restrict__ bias,
    const float* __restrict__ ln_g, const float* __restrict__ ln_b,
    unsigned short* __restrict__ outb, int N) {
  constexpr int C = HC / H;
  int n = blockIdx.x;
  int tid = threadIdx.x;
  int c0 = tid * VEC;
  int head = c0 / C;
  int beg = row_ptr[n], end = row_ptr[n + 1];
  float acc[VEC];
#pragma unroll
  for (int i = 0; i < VEC; i++) acc[i] = 0.f;
  for (int j = beg; j < end; j++) {
    int srcn = src_sorted[j];
    float p = p_sorted[(size_t)j * H + head];
    const unsigned short* hp = hbuf + (size_t)srcn * HC + c0;
    if constexpr (VEC == 4) {
      ushort4 u = *reinterpret_cast<const ushort4*>(hp);
      acc[0] = fmaf(p, bf2f(u.x), acc[0]);
      acc[1] = fmaf(p, bf2f(u.y), acc[1]);
      acc[2] = fmaf(p, bf2f(u.z), acc[2]);
      acc[3] = fmaf(p, bf2f(u.w), acc[3]);
    } else {
      ushort2 u = *reinterpret_cast<const ushort2*>(hp);
      acc[0] = fmaf(p, bf2f(u.x), acc[0]);
      acc[1] = fmaf(p, bf2f(u.y), acc[1]);
    }
  }
  float scale = inv_den[(size_t)n * H + head];
  float v[VEC]; float s1 = 0.f, s2 = 0.f;
#pragma unroll
  for (int i = 0; i < VEC; i++) {
    v[i] = acc[i] * scale + bias[c0 + i];
    s1 += v[i]; s2 += v[i] * v[i];
  }
#pragma unroll
  for (int o = 32; o; o >>= 1) { s1 += __shfl_down(s1, o); s2 += __shfl_down(s2, o); }
  __shared__ float r1[4], r2[4];
  int wave = tid >> 6, lane = tid & 63;
  if (lane == 0) { r1[wave] = s1; r2[wave] = s2; }
  __syncthreads();
  float t1 = r1[0] + r1[1] + r1[2] + r1[3];
  float t2 = r2[0] + r2[1] + r2[2] + r2[3];
  float mean = t1 * (1.0f / HC);
  float var = t2 * (1.0f / HC) - mean * mean;
  float rstd = rsqrtf(var + 1e-5f);
#pragma unroll
  for (int i = 0; i < VEC; i++) {
    float y = (v[i] - mean) * rstd * ln_g[c0 + i] + ln_b[c0 + i];
    y = y > 0.f ? y : NEG_ACT * y;
    outb[(size_t)n * HC + c0 + i] = f2bf(y);
  }
}

// ---------------------------------------------------------------------------
// Layer-3 aggregation + bias + LN(32) + log_softmax(32) -> f32 output.
// ---------------------------------------------------------------------------
__global__ __launch_bounds__(256) void final_kernel(
    const int* __restrict__ row_ptr, const int* __restrict__ src_sorted,
    const float* __restrict__ p_sorted, const float* __restrict__ inv_den,
    const unsigned short* __restrict__ h3, const float* __restrict__ b3,
    const float* __restrict__ g3, const float* __restrict__ bb3,
    float* __restrict__ out, int N) {
  int idx = blockIdx.x * 256 + threadIdx.x;
  int n = idx >> 5, c = idx & 31;
  if (n >= N) return;
  int beg = row_ptr[n], end = row_ptr[n + 1];
  float acc = 0.f;
  for (int j = beg; j < end; j++)
    acc = fmaf(p_sorted[j], bf2f(h3[(size_t)src_sorted[j] * 32 + c]), acc);
  float v = acc * inv_den[n] + b3[c];
  float s1 = v, s2 = v * v;
#pragma unroll
  for (int o = 16; o; o >>= 1) { s1 += __shfl_xor(s1, o, 32); s2 += __shfl_xor(s2, o, 32); }
  float mean = s1 * (1.f / 32.f), var = s2 * (1.f / 32.f) - mean * mean;
  float y = (v - mean) * rsqrtf(var + 1e-5f) * g3[c] + bb3[c];
  float mx = y;
#pragma unroll
  for (int o = 16; o; o >>= 1) mx = fmaxf(mx, __shfl_xor(mx, o, 32));
  float ex = __expf(y - mx), se = ex;
#pragma unroll
  for (int o = 16; o; o >>= 1) se += __shfl_xor(se, o, 32);
  out[(size_t)n * 32 + c] = y - mx - __logf(se);
}

// ---------------------------------------------------------------------------
extern "C" void kernel_launch(void* const* d_in, const int* in_sizes, int n_in,
                              void* d_out, int out_size, void* d_ws,
                              size_t ws_size, hipStream_t stream) {
  const float* x   = (const float*)d_in[0];
  const int* esrc  = (const int*)d_in[1];
  const int* edst  = (const int*)d_in[2];
  const float* W1  = (const float*)d_in[3];
  const float* as1 = (const float*)d_in[4];
  const float* ad1 = (const float*)d_in[5];
  const float* b1  = (const float*)d_in[6];
  const float* g1  = (const float*)d_in[7];
  const float* bb1 = (const float*)d_in[8];
  const float* W2  = (const float*)d_in[9];
  const float* as2 = (const float*)d_in[10];
  const float* ad2 = (const float*)d_in[11];
  const float* b2  = (const float*)d_in[12];
  const float* g2  = (const float*)d_in[13];
  const float* bb2 = (const float*)d_in[14];
  const float* W3  = (const float*)d_in[15];
  const float* as3 = (const float*)d_in[16];
  const float* ad3 = (const float*)d_in[17];
  const float* b3  = (const float*)d_in[18];
  const float* g3  = (const float*)d_in[19];
  const float* bb3 = (const float*)d_in[20];
  float* out = (float*)d_out;

  const int N = in_sizes[0] / 256;   // 50000
  const int E = in_sizes[1];         // 400000
  const int Etot = E + N;

  char* ws = (char*)d_ws;
  size_t off = 0;
  auto alloc = [&](size_t bytes) -> char* {
    char* p = ws + off;
    off += (bytes + 255) & ~(size_t)255;
    return p;
  };
  int* cnt        = (int*)alloc((size_t)(N + 1) * 4);
  int* cur        = (int*)alloc((size_t)(N + 1) * 4);
  int* row_ptr    = (int*)alloc((size_t)(N + 1) * 4);
  int* src_sorted = (int*)alloc((size_t)Etot * 4);
  float* s1    = (float*)alloc((size_t)N * 4 * 4);
  float* d1    = (float*)alloc((size_t)N * 4 * 4);
  float* invd1 = (float*)alloc((size_t)N * 4 * 4);
  float* p1    = (float*)alloc((size_t)Etot * 4 * 4);
  float* s2    = (float*)alloc((size_t)N * 4 * 4);
  float* d2    = (float*)alloc((size_t)N * 4 * 4);
  float* invd2 = (float*)alloc((size_t)N * 4 * 4);
  float* p2    = (float*)alloc((size_t)Etot * 4 * 4);
  float* s3    = (float*)alloc((size_t)N * 4);
  float* d3    = (float*)alloc((size_t)N * 4);
  float* invd3 = (float*)alloc((size_t)N * 4);
  float* p3    = (float*)alloc((size_t)Etot * 4);
  unsigned short* W1b = (unsigned short*)alloc((size_t)1024 * 256 * 2);
  unsigned short* W2b = (unsigned short*)alloc((size_t)512 * 1024 * 2);
  unsigned short* W3b = (unsigned short*)alloc((size_t)32 * 512 * 2);
  unsigned short* h1   = (unsigned short*)alloc((size_t)N * 1024 * 2);
  unsigned short* act1 = (unsigned short*)alloc((size_t)N * 1024 * 2);
  // overlays: xb (bf16 x, [N,256]) lives in act1's region (dead before agg1
  // writes act1). h2 overlays h1 (h1 dead after agg1); act2 overlays h1's
  // second half; h3 overlays act1 (act1 dead after GEMM2).
  unsigned short* xb   = act1;
  unsigned short* h2   = h1;
  unsigned short* act2 = (unsigned short*)((char*)h1 + (size_t)N * 512 * 2);
  unsigned short* h3   = act1;

  // ---- bf16 conversions ----
  cvt_kernel<<<(N * 256 / 8 + 255) / 256, 256, 0, stream>>>(x, xb, N * 256 / 8);
  cvt_kernel<<<(1024 * 256 / 8 + 255) / 256, 256, 0, stream>>>(W1, W1b, 1024 * 256 / 8);
  cvt_kernel<<<(512 * 1024 / 8 + 255) / 256, 256, 0, stream>>>(W2, W2b, 512 * 1024 / 8);
  cvt_kernel<<<(32 * 512 / 8 + 255) / 256, 256, 0, stream>>>(W3, W3b, 32 * 512 / 8);

  // ---- CSR by dst ----
  hipMemsetAsync(cnt, 0, (size_t)(N + 1) * 4, stream);
  int eb = (Etot + 255) / 256;
  hist_kernel<<<eb, 256, 0, stream>>>(edst, cnt, E, N);
  scan_kernel<<<1, 1024, 0, stream>>>(cnt, row_ptr, cur, N);
  scatter_kernel<<<eb, 256, 0, stream>>>(esrc, edst, cur, src_sorted, E, N);

  int mb = (N + 127) / 128;
  // ---- layer 1 ----
  gemm_mfma<128, 128, 2, 2>
      <<<dim3(mb, 1024 / 128), 256, 0, stream>>>(xb, W1b, h1, N, 1024, 256);
  sd_kernel<256><<<N, 256, 0, stream>>>(h1, as1, ad1, s1, d1, N);
  stats_kernel<<<(N * 4 + 255) / 256, 256, 0, stream>>>(row_ptr, src_sorted,
                                                        s1, d1, p1, invd1, N, 4);
  agg_ln_kernel<1024, 4, 4><<<N, 256, 0, stream>>>(row_ptr, src_sorted, p1,
      invd1, h1, b1, g1, bb1, act1, N);
  // ---- layer 2 ----
  gemm_mfma<128, 128, 2, 2>
      <<<dim3(mb, 512 / 128), 256, 0, stream>>>(act1, W2b, h2, N, 512, 1024);
  sd_kernel<128><<<N, 256, 0, stream>>>(h2, as2, ad2, s2, d2, N);
  stats_kernel<<<(N * 4 + 255) / 256, 256, 0, stream>>>(row_ptr, src_sorted,
                                                        s2, d2, p2, invd2, N, 4);
  agg_ln_kernel<512, 4, 2><<<N, 256, 0, stream>>>(row_ptr, src_sorted, p2,
      invd2, h2, b2, g2, bb2, act2, N);
  // ---- layer 3 ----
  gemm_mfma<128, 32, 4, 1>
      <<<dim3(mb, 1), 256, 0, stream>>>(act2, W3b, h3, N, 32, 512);
  sd32_kernel<<<(N * 32 + 255) / 256, 256, 0, stream>>>(h3, as3, ad3, s3, d3, N);
  stats_kernel<<<(N + 255) / 256, 256, 0, stream>>>(row_ptr, src_sorted,
                                                    s3, d3, p3, invd3, N, 1);
  final_kernel<<<(N * 32 + 255) / 256, 256, 0, stream>>>(row_ptr, src_sorted,
      p3, invd3, h3, b3, g3, bb3, out, N);
}

// Round 3
// 781.739 us; speedup vs baseline: 2.1418x; 1.0842x over previous
//
#include <hip/hip_runtime.h>
#include <math.h>

// ---------------------------------------------------------------------------
// GAT 3-layer forward, MI355X. Round 3:
//  - Layer 1 restructured: aggregate in INPUT space (512B rows, 4x less
//    gather traffic); attention coeffs from x via Q = W^T a (tiny GEMM);
//    per-head GEMM runs after aggregation (bias fused), then LN+leaky pass.
//  - Segment softmax fused into aggregation (3-pass wave-per-node, LDS
//    alphas) for layers 1&2 -- stats kernels and p/inv_den buffers gone.
//  - MFMA GEMM generalized: lda/ldb/ldc + grid.z head offsets + bias + f32 out.
// ---------------------------------------------------------------------------

#define NEG_ATT 0.2f
#define NEG_ACT 0.01f

typedef __attribute__((ext_vector_type(8))) short bf16x8;
typedef __attribute__((ext_vector_type(8))) unsigned short u16x8;
typedef __attribute__((ext_vector_type(4))) float f32x4;

__device__ __forceinline__ float bf2f(unsigned short u) {
  union { unsigned int i; float f; } c; c.i = ((unsigned int)u) << 16; return c.f;
}
__device__ __forceinline__ unsigned short f2bf(float f) {
  union { float f; unsigned int i; } c; c.f = f;
  unsigned int r = c.i + 0x7FFFu + ((c.i >> 16) & 1u);
  return (unsigned short)(r >> 16);
}

// ---------------------------------------------------------------------------
// f32 -> bf16 bulk convert (n divisible by 8)
// ---------------------------------------------------------------------------
__global__ void cvt_kernel(const float* __restrict__ in,
                           unsigned short* __restrict__ out, int n8) {
  int i = blockIdx.x * 256 + threadIdx.x;
  if (i >= n8) return;
  float4 v0 = reinterpret_cast<const float4*>(in)[i * 2];
  float4 v1 = reinterpret_cast<const float4*>(in)[i * 2 + 1];
  ushort4 o0 = make_ushort4(f2bf(v0.x), f2bf(v0.y), f2bf(v0.z), f2bf(v0.w));
  ushort4 o1 = make_ushort4(f2bf(v1.x), f2bf(v1.y), f2bf(v1.z), f2bf(v1.w));
  reinterpret_cast<ushort4*>(out)[i * 2] = o0;
  reinterpret_cast<ushort4*>(out)[i * 2 + 1] = o1;
}

// ---------------------------------------------------------------------------
// Qb[16][256] bf16: rows 0..3 = W1_h^T a_src,h ; rows 4..7 = W1_h^T a_dst,h ;
// rows 8..15 zero (MFMA N-pad). grid 16 blocks x 256 threads (thread = k).
// ---------------------------------------------------------------------------
__global__ __launch_bounds__(256) void qb_kernel(const float* __restrict__ W1,
    const float* __restrict__ as1, const float* __restrict__ ad1,
    unsigned short* __restrict__ Qb) {
  int r = blockIdx.x;          // output row
  int k = threadIdx.x;         // 0..255
  if (r >= 8) { Qb[r * 256 + k] = 0; return; }
  int h = r & 3;
  const float* av = (r >> 2) ? ad1 : as1;
  float acc = 0.f;
#pragma unroll 8
  for (int c = 0; c < 256; c++)
    acc += W1[((size_t)(h * 256 + c)) * 256 + k] * av[h * 256 + c];
  Qb[r * 256 + k] = f2bf(acc);
}

// ---------------------------------------------------------------------------
// CSR build: histogram -> exclusive scan -> scatter (src sorted by dst)
// ---------------------------------------------------------------------------
__global__ void hist_kernel(const int* __restrict__ edge_dst,
                            int* __restrict__ cnt, int E, int N) {
  int e = blockIdx.x * 256 + threadIdx.x;
  if (e >= E + N) return;
  int dn = (e < E) ? edge_dst[e] : (e - E);   // self-loops appended
  atomicAdd(&cnt[dn], 1);
}

__global__ __launch_bounds__(1024) void scan_kernel(const int* __restrict__ cnt,
    int* __restrict__ row_ptr, int* __restrict__ cur, int N) {
  __shared__ int sbuf[1024];
  int tid = threadIdx.x;
  int CH = (N + 1023) / 1024;
  int beg = tid * CH;
  int end = beg + CH; if (end > N) end = N;
  int lsum = 0;
  for (int i = beg; i < end; i++) lsum += cnt[i];
  sbuf[tid] = lsum;
  __syncthreads();
  for (int off = 1; off < 1024; off <<= 1) {
    int v = (tid >= off) ? sbuf[tid - off] : 0;
    __syncthreads();
    sbuf[tid] += v;
    __syncthreads();
  }
  int run = sbuf[tid] - lsum;  // exclusive prefix
  for (int i = beg; i < end; i++) {
    row_ptr[i] = run; cur[i] = run;
    run += cnt[i];
  }
  if (tid == 1023) row_ptr[N] = sbuf[1023];
}

__global__ void scatter_kernel(const int* __restrict__ edge_src,
                               const int* __restrict__ edge_dst,
                               int* __restrict__ cur,
                               int* __restrict__ src_sorted, int E, int N) {
  int e = blockIdx.x * 256 + threadIdx.x;
  if (e >= E + N) return;
  int sn, dn;
  if (e < E) { sn = edge_src[e]; dn = edge_dst[e]; }
  else       { sn = dn = e - E; }
  int pos = atomicAdd(&cur[dn], 1);
  src_sorted[pos] = sn;
}

// ---------------------------------------------------------------------------
// MFMA bf16 GEMM: C[m][n] = sum_k A[m][k]*B[n][k] (+ bias[n]).
// Strided + grid.z offsets (per-head batching) + optional f32 output.
// 256 threads = 4 waves, XOR-swizzled LDS, global_load_lds width-16 staging.
// ---------------------------------------------------------------------------
#define GLOBAL_AS __attribute__((address_space(1)))
#define LDS_AS __attribute__((address_space(3)))

__device__ __forceinline__ void gload_lds16(const void* g, void* l) {
  __builtin_amdgcn_global_load_lds((const GLOBAL_AS unsigned int*)g,
                                   (LDS_AS unsigned int*)l, 16, 0, 0);
}

template <int BM, int BN, int WM, int WN, bool F32OUT>
__global__ __launch_bounds__(256) void gemm_mfma(
    const unsigned short* __restrict__ A, const unsigned short* __restrict__ B,
    void* __restrict__ Cv, const float* __restrict__ bias,
    int M, int N, int K, int lda, int ldb, int ldc,
    long long aZ, long long bZ, long long cZ, int biasZ) {
  constexpr int BK = 64;
  constexpr int FM = BM / (WM * 16);
  constexpr int FN = BN / (WN * 16);
  A += (size_t)blockIdx.z * aZ;
  B += (size_t)blockIdx.z * bZ;
  const size_t cbase = (size_t)blockIdx.z * cZ;
  __shared__ unsigned short As[BM * BK];
  __shared__ unsigned short Bs[BN * BK];
  const int tid = threadIdx.x;
  const int w = tid >> 6, lane = tid & 63;
  const int wm = w / WN, wn = w % WN;
  const int bm = blockIdx.x * BM, bn = blockIdx.y * BN;
  const int l15 = lane & 15, l4 = lane >> 4;

  f32x4 acc[FM][FN] = {};

  constexpr int CHA = BM * BK / 8;   // 16B chunks in A tile
  constexpr int CHB = BN * BK / 8;

  for (int k0 = 0; k0 < K; k0 += BK) {
#pragma unroll
    for (int c0 = 0; c0 < CHA; c0 += 256) {
      int c = c0 + tid;
      if (CHA - c0 >= 256 || tid < CHA - c0) {
        int cl = c ^ ((c >> 3) & 7);
        int row = cl >> 3;
        int kk = (cl & 7) * 8;
        int gr = bm + row; if (gr > M - 1) gr = M - 1;
        gload_lds16(A + (size_t)gr * lda + k0 + kk,
                    As + (size_t)(c0 + (tid & ~63)) * 8);
      }
    }
#pragma unroll
    for (int c0 = 0; c0 < CHB; c0 += 256) {
      int c = c0 + tid;
      if (CHB - c0 >= 256 || tid < CHB - c0) {
        int cl = c ^ ((c >> 3) & 7);
        int row = cl >> 3;
        int kk = (cl & 7) * 8;
        gload_lds16(B + (size_t)(bn + row) * ldb + k0 + kk,
                    Bs + (size_t)(c0 + (tid & ~63)) * 8);
      }
    }
    __syncthreads();
#pragma unroll
    for (int ks = 0; ks < 2; ks++) {
      bf16x8 af[FM], bfr[FN];
#pragma unroll
      for (int i = 0; i < FM; i++) {
        int row = wm * (FM * 16) + i * 16 + l15;
        int byte = row * (BK * 2) + ks * 64 + l4 * 16;
        byte ^= ((byte >> 7) & 7) << 4;
        af[i] = *reinterpret_cast<const bf16x8*>((const char*)As + byte);
      }
#pragma unroll
      for (int i = 0; i < FN; i++) {
        int row = wn * (FN * 16) + i * 16 + l15;
        int byte = row * (BK * 2) + ks * 64 + l4 * 16;
        byte ^= ((byte >> 7) & 7) << 4;
        bfr[i] = *reinterpret_cast<const bf16x8*>((const char*)Bs + byte);
      }
#pragma unroll
      for (int i = 0; i < FM; i++)
#pragma unroll
        for (int jn = 0; jn < FN; jn++)
          acc[i][jn] = __builtin_amdgcn_mfma_f32_16x16x32_bf16(
              af[i], bfr[jn], acc[i][jn], 0, 0, 0);
    }
    __syncthreads();
  }
  // epilogue: D col = lane&15, row = (lane>>4)*4 + reg (HW-verified)
#pragma unroll
  for (int i = 0; i < FM; i++) {
#pragma unroll
    for (int jn = 0; jn < FN; jn++) {
      int col = bn + wn * (FN * 16) + jn * 16 + l15;
      float bv = bias ? bias[biasZ * blockIdx.z + col] : 0.f;
#pragma unroll
      for (int r = 0; r < 4; r++) {
        int m = bm + wm * (FM * 16) + i * 16 + l4 * 4 + r;
        if (m < M) {
          float val = acc[i][jn][r] + bv;
          if constexpr (F32OUT)
            ((float*)Cv)[cbase + (size_t)m * ldc + col] = val;
          else
            ((unsigned short*)Cv)[cbase + (size_t)m * ldc + col] = f2bf(val);
        }
      }
    }
  }
}

// ---------------------------------------------------------------------------
// Layer-1 fused softmax + INPUT-space aggregation.
// sd1[n][0..3]=s heads, [4..7]=d heads (f32, from the Qb GEMM).
// One wave per node (4 nodes/block). 3 passes over edges: max, den, acc.
// y[n][h*256+c] = sum_j alpha_jh * x[src_j][c], written bf16.
// ---------------------------------------------------------------------------
__global__ __launch_bounds__(256) void aggx_kernel(
    const int* __restrict__ row_ptr, const int* __restrict__ src_sorted,
    const float* __restrict__ sd1, const unsigned short* __restrict__ xb,
    unsigned short* __restrict__ y, int N) {
  __shared__ float alds[4][2][64][4];
  int w = threadIdx.x >> 6, lane = threadIdx.x & 63;
  int n = blockIdx.x * 4 + w;
  if (n >= N) return;
  int beg = row_ptr[n], end = row_ptr[n + 1];
  float4 dv = *reinterpret_cast<const float4*>(sd1 + (size_t)n * 16 + 4);

  auto compE = [&](int t, float e[4]) {
    if (t < end) {
      int sj = src_sorted[t];
      float4 sv = *reinterpret_cast<const float4*>(sd1 + (size_t)sj * 16);
      e[0] = sv.x + dv.x; e[1] = sv.y + dv.y;
      e[2] = sv.z + dv.z; e[3] = sv.w + dv.w;
#pragma unroll
      for (int h = 0; h < 4; h++) e[h] = e[h] > 0.f ? e[h] : NEG_ATT * e[h];
    } else {
      e[0] = e[1] = e[2] = e[3] = -1e30f;
    }
  };

  float mx[4] = {-1e30f, -1e30f, -1e30f, -1e30f};
  for (int cb = beg; cb < end; cb += 64) {
    float e[4]; compE(cb + lane, e);
#pragma unroll
    for (int h = 0; h < 4; h++) {
      float m = e[h];
#pragma unroll
      for (int o = 32; o; o >>= 1) m = fmaxf(m, __shfl_xor(m, o));
      mx[h] = fmaxf(mx[h], m);
    }
  }
  float den[4] = {0.f, 0.f, 0.f, 0.f};
  for (int cb = beg; cb < end; cb += 64) {
    float e[4]; compE(cb + lane, e);
#pragma unroll
    for (int h = 0; h < 4; h++) {
      float p = __expf(e[h] - mx[h]);
#pragma unroll
      for (int o = 32; o; o >>= 1) p += __shfl_xor(p, o);
      den[h] += p;
    }
  }
  float ia[4];
#pragma unroll
  for (int h = 0; h < 4; h++) ia[h] = 1.0f / (den[h] + 1e-16f);

  float acc[4][4] = {};
  for (int cb = beg; cb < end; cb += 64) {
    float e[4]; compE(cb + lane, e);
    int pb = ((cb - beg) >> 6) & 1;
    float4 al;
    al.x = __expf(e[0] - mx[0]) * ia[0];
    al.y = __expf(e[1] - mx[1]) * ia[1];
    al.z = __expf(e[2] - mx[2]) * ia[2];
    al.w = __expf(e[3] - mx[3]) * ia[3];
    *reinterpret_cast<float4*>(alds[w][pb][lane]) = al;
    int cd = end - cb; if (cd > 64) cd = 64;
    for (int j = 0; j < cd; j++) {
      float4 a4 = *reinterpret_cast<const float4*>(alds[w][pb][j]);
      int sj = src_sorted[cb + j];
      ushort4 xv = *reinterpret_cast<const ushort4*>(
          xb + (size_t)sj * 256 + lane * 4);
      float x0 = bf2f(xv.x), x1 = bf2f(xv.y), x2 = bf2f(xv.z), x3 = bf2f(xv.w);
      float ar[4] = {a4.x, a4.y, a4.z, a4.w};
#pragma unroll
      for (int h = 0; h < 4; h++) {
        acc[h][0] = fmaf(ar[h], x0, acc[h][0]);
        acc[h][1] = fmaf(ar[h], x1, acc[h][1]);
        acc[h][2] = fmaf(ar[h], x2, acc[h][2]);
        acc[h][3] = fmaf(ar[h], x3, acc[h][3]);
      }
    }
  }
#pragma unroll
  for (int h = 0; h < 4; h++) {
    ushort4 o = make_ushort4(f2bf(acc[h][0]), f2bf(acc[h][1]),
                             f2bf(acc[h][2]), f2bf(acc[h][3]));
    *reinterpret_cast<ushort4*>(y + (size_t)n * 1024 + h * 256 + lane * 4) = o;
  }
}

// ---------------------------------------------------------------------------
// Layer-2 fused softmax + aggregation + bias + LN(512) + leaky_relu.
// One wave per node (4 nodes/block); lane holds 8 channels (head = lane/16).
// ---------------------------------------------------------------------------
__global__ __launch_bounds__(256) void agg2m_kernel(
    const int* __restrict__ row_ptr, const int* __restrict__ src_sorted,
    const float* __restrict__ s2, const float* __restrict__ d2,
    const unsigned short* __restrict__ h2, const float* __restrict__ bias,
    const float* __restrict__ ln_g, const float* __restrict__ ln_b,
    unsigned short* __restrict__ outb, int N) {
  __shared__ float alds[4][2][64][4];
  int w = threadIdx.x >> 6, lane = threadIdx.x & 63;
  int n = blockIdx.x * 4 + w;
  if (n >= N) return;
  int beg = row_ptr[n], end = row_ptr[n + 1];
  int head = lane >> 4, c0 = lane * 8;
  float4 dv = *reinterpret_cast<const float4*>(d2 + (size_t)n * 4);

  auto compE = [&](int t, float e[4]) {
    if (t < end) {
      int sj = src_sorted[t];
      float4 sv = *reinterpret_cast<const float4*>(s2 + (size_t)sj * 4);
      e[0] = sv.x + dv.x; e[1] = sv.y + dv.y;
      e[2] = sv.z + dv.z; e[3] = sv.w + dv.w;
#pragma unroll
      for (int h = 0; h < 4; h++) e[h] = e[h] > 0.f ? e[h] : NEG_ATT * e[h];
    } else {
      e[0] = e[1] = e[2] = e[3] = -1e30f;
    }
  };

  float mx[4] = {-1e30f, -1e30f, -1e30f, -1e30f};
  for (int cb = beg; cb < end; cb += 64) {
    float e[4]; compE(cb + lane, e);
#pragma unroll
    for (int h = 0; h < 4; h++) {
      float m = e[h];
#pragma unroll
      for (int o = 32; o; o >>= 1) m = fmaxf(m, __shfl_xor(m, o));
      mx[h] = fmaxf(mx[h], m);
    }
  }
  float den[4] = {0.f, 0.f, 0.f, 0.f};
  for (int cb = beg; cb < end; cb += 64) {
    float e[4]; compE(cb + lane, e);
#pragma unroll
    for (int h = 0; h < 4; h++) {
      float p = __expf(e[h] - mx[h]);
#pragma unroll
      for (int o = 32; o; o >>= 1) p += __shfl_xor(p, o);
      den[h] += p;
    }
  }
  float ia[4];
#pragma unroll
  for (int h = 0; h < 4; h++) ia[h] = 1.0f / (den[h] + 1e-16f);

  float acc[8] = {};
  for (int cb = beg; cb < end; cb += 64) {
    float e[4]; compE(cb + lane, e);
    int pb = ((cb - beg) >> 6) & 1;
    float4 al;
    al.x = __expf(e[0] - mx[0]) * ia[0];
    al.y = __expf(e[1] - mx[1]) * ia[1];
    al.z = __expf(e[2] - mx[2]) * ia[2];
    al.w = __expf(e[3] - mx[3]) * ia[3];
    *reinterpret_cast<float4*>(alds[w][pb][lane]) = al;
    int cd = end - cb; if (cd > 64) cd = 64;
    for (int j = 0; j < cd; j++) {
      float a = alds[w][pb][j][head];
      int sj = src_sorted[cb + j];
      u16x8 xv = *reinterpret_cast<const u16x8*>(h2 + (size_t)sj * 512 + c0);
#pragma unroll
      for (int i = 0; i < 8; i++)
        acc[i] = fmaf(a, bf2f(xv[i]), acc[i]);
    }
  }
  // bias + LN(512) + leaky, all within the wave
  float v[8], s1 = 0.f, sq = 0.f;
#pragma unroll
  for (int i = 0; i < 8; i++) {
    v[i] = acc[i] + bias[c0 + i];
    s1 += v[i]; sq += v[i] * v[i];
  }
#pragma unroll
  for (int o = 32; o; o >>= 1) { s1 += __shfl_xor(s1, o); sq += __shfl_xor(sq, o); }
  float mean = s1 * (1.0f / 512.0f);
  float var = sq * (1.0f / 512.0f) - mean * mean;
  float rstd = rsqrtf(var + 1e-5f);
  u16x8 ov;
#pragma unroll
  for (int i = 0; i < 8; i++) {
    float yv = (v[i] - mean) * rstd * ln_g[c0 + i] + ln_b[c0 + i];
    yv = yv > 0.f ? yv : NEG_ACT * yv;
    ov[i] = f2bf(yv);
  }
  *reinterpret_cast<u16x8*>(outb + (size_t)n * 512 + c0) = ov;
}

// ---------------------------------------------------------------------------
// LN(1024) + leaky over z1 -> act1 (bias already folded into GEMM epilogue).
// One node per block, 256 threads x 4 channels.
// ---------------------------------------------------------------------------
__global__ __launch_bounds__(256) void ln1024_kernel(
    const unsigned short* __restrict__ z, const float* __restrict__ ln_g,
    const float* __restrict__ ln_b, unsigned short* __restrict__ outb, int N) {
  int n = blockIdx.x;
  int tid = threadIdx.x;
  int c0 = tid * 4;
  ushort4 zv = *reinterpret_cast<const ushort4*>(z + (size_t)n * 1024 + c0);
  float v[4] = {bf2f(zv.x), bf2f(zv.y), bf2f(zv.z), bf2f(zv.w)};
  float s1 = v[0] + v[1] + v[2] + v[3];
  float sq = v[0]*v[0] + v[1]*v[1] + v[2]*v[2] + v[3]*v[3];
#pragma unroll
  for (int o = 32; o; o >>= 1) { s1 += __shfl_down(s1, o); sq += __shfl_down(sq, o); }
  __shared__ float r1[4], r2[4];
  int wave = tid >> 6, lane = tid & 63;
  if (lane == 0) { r1[wave] = s1; r2[wave] = sq; }
  __syncthreads();
  float t1 = r1[0] + r1[1] + r1[2] + r1[3];
  float t2 = r2[0] + r2[1] + r2[2] + r2[3];
  float mean = t1 * (1.0f / 1024.0f);
  float var = t2 * (1.0f / 1024.0f) - mean * mean;
  float rstd = rsqrtf(var + 1e-5f);
  ushort4 ov;
  float y0 = (v[0] - mean) * rstd * ln_g[c0 + 0] + ln_b[c0 + 0];
  float y1 = (v[1] - mean) * rstd * ln_g[c0 + 1] + ln_b[c0 + 1];
  float y2 = (v[2] - mean) * rstd * ln_g[c0 + 2] + ln_b[c0 + 2];
  float y3 = (v[3] - mean) * rstd * ln_g[c0 + 3] + ln_b[c0 + 3];
  ov.x = f2bf(y0 > 0.f ? y0 : NEG_ACT * y0);
  ov.y = f2bf(y1 > 0.f ? y1 : NEG_ACT * y1);
  ov.z = f2bf(y2 > 0.f ? y2 : NEG_ACT * y2);
  ov.w = f2bf(y3 > 0.f ? y3 : NEG_ACT * y3);
  *reinterpret_cast<ushort4*>(outb + (size_t)n * 1024 + c0) = ov;
}

// ---------------------------------------------------------------------------
// s/d for layer 2 (H=4, C=128): one block per node, one wave per head.
// ---------------------------------------------------------------------------
__global__ __launch_bounds__(256) void sd128_kernel(
    const unsigned short* __restrict__ h, const float* __restrict__ a_src,
    const float* __restrict__ a_dst, float* __restrict__ s,
    float* __restrict__ d, int N) {
  int n = blockIdx.x;
  int head = threadIdx.x >> 6;
  int lane = threadIdx.x & 63;
  const unsigned short* row = h + (size_t)n * 512 + head * 128 + lane * 2;
  ushort2 u = *reinterpret_cast<const ushort2*>(row);
  float2 a = *reinterpret_cast<const float2*>(a_src + head * 128 + lane * 2);
  float2 b = *reinterpret_cast<const float2*>(a_dst + head * 128 + lane * 2);
  float ss = bf2f(u.x) * a.x + bf2f(u.y) * a.y;
  float dd = bf2f(u.x) * b.x + bf2f(u.y) * b.y;
#pragma unroll
  for (int o = 32; o; o >>= 1) { ss += __shfl_down(ss, o); dd += __shfl_down(dd, o); }
  if (lane == 0) { s[(size_t)n * 4 + head] = ss; d[(size_t)n * 4 + head] = dd; }
}

// layer 3: H=1, C=32
__global__ __launch_bounds__(256) void sd32_kernel(
    const unsigned short* __restrict__ h, const float* __restrict__ a_src,
    const float* __restrict__ a_dst, float* __restrict__ s,
    float* __restrict__ d, int N) {
  int idx = blockIdx.x * 256 + threadIdx.x;
  int n = idx >> 5, c = idx & 31;
  if (n >= N) return;
  float v = bf2f(h[(size_t)n * 32 + c]);
  float ss = v * a_src[c], dd = v * a_dst[c];
#pragma unroll
  for (int o = 16; o; o >>= 1) { ss += __shfl_xor(ss, o, 32); dd += __shfl_xor(dd, o, 32); }
  if (c == 0) { s[n] = ss; d[n] = dd; }
}

// ---------------------------------------------------------------------------
// Layer-3 softmax stats (H=1) -- kept separate (tiny).
// ---------------------------------------------------------------------------
__global__ void stats_kernel(const int* __restrict__ row_ptr,
    const int* __restrict__ src_sorted, const float* __restrict__ s,
    const float* __restrict__ d, float* __restrict__ p_sorted,
    float* __restrict__ inv_den, int N) {
  int idx = blockIdx.x * blockDim.x + threadIdx.x;
  if (idx >= N) return;
  int n = idx;
  int beg = row_ptr[n], end = row_ptr[n + 1];
  float dn = d[n];
  float mx = -1e30f;
  for (int j = beg; j < end; j++) {
    float v = s[src_sorted[j]] + dn;
    v = v > 0.f ? v : NEG_ATT * v;
    mx = fmaxf(mx, v);
  }
  float den = 0.f;
  for (int j = beg; j < end; j++) {
    float v = s[src_sorted[j]] + dn;
    v = v > 0.f ? v : NEG_ATT * v;
    float p = __expf(v - mx);
    p_sorted[j] = p;
    den += p;
  }
  inv_den[n] = 1.0f / (den + 1e-16f);
}

// ---------------------------------------------------------------------------
// Layer-3 aggregation + bias + LN(32) + log_softmax(32) -> f32 output.
// ---------------------------------------------------------------------------
__global__ __launch_bounds__(256) void final_kernel(
    const int* __restrict__ row_ptr, const int* __restrict__ src_sorted,
    const float* __restrict__ p_sorted, const float* __restrict__ inv_den,
    const unsigned short* __restrict__ h3, const float* __restrict__ b3,
    const float* __restrict__ g3, const float* __restrict__ bb3,
    float* __restrict__ out, int N) {
  int idx = blockIdx.x * 256 + threadIdx.x;
  int n = idx >> 5, c = idx & 31;
  if (n >= N) return;
  int beg = row_ptr[n], end = row_ptr[n + 1];
  float acc = 0.f;
  for (int j = beg; j < end; j++)
    acc = fmaf(p_sorted[j], bf2f(h3[(size_t)src_sorted[j] * 32 + c]), acc);
  float v = acc * inv_den[n] + b3[c];
  float s1 = v, s2 = v * v;
#pragma unroll
  for (int o = 16; o; o >>= 1) { s1 += __shfl_xor(s1, o, 32); s2 += __shfl_xor(s2, o, 32); }
  float mean = s1 * (1.f / 32.f), var = s2 * (1.f / 32.f) - mean * mean;
  float y = (v - mean) * rsqrtf(var + 1e-5f) * g3[c] + bb3[c];
  float mx = y;
#pragma unroll
  for (int o = 16; o; o >>= 1) mx = fmaxf(mx, __shfl_xor(mx, o, 32));
  float ex = __expf(y - mx), se = ex;
#pragma unroll
  for (int o = 16; o; o >>= 1) se += __shfl_xor(se, o, 32);
  out[(size_t)n * 32 + c] = y - mx - __logf(se);
}

// ---------------------------------------------------------------------------
extern "C" void kernel_launch(void* const* d_in, const int* in_sizes, int n_in,
                              void* d_out, int out_size, void* d_ws,
                              size_t ws_size, hipStream_t stream) {
  const float* x   = (const float*)d_in[0];
  const int* esrc  = (const int*)d_in[1];
  const int* edst  = (const int*)d_in[2];
  const float* W1  = (const float*)d_in[3];
  const float* as1 = (const float*)d_in[4];
  const float* ad1 = (const float*)d_in[5];
  const float* b1  = (const float*)d_in[6];
  const float* g1  = (const float*)d_in[7];
  const float* bb1 = (const float*)d_in[8];
  const float* W2  = (const float*)d_in[9];
  const float* as2 = (const float*)d_in[10];
  const float* ad2 = (const float*)d_in[11];
  const float* b2  = (const float*)d_in[12];
  const float* g2  = (const float*)d_in[13];
  const float* bb2 = (const float*)d_in[14];
  const float* W3  = (const float*)d_in[15];
  const float* as3 = (const float*)d_in[16];
  const float* ad3 = (const float*)d_in[17];
  const float* b3  = (const float*)d_in[18];
  const float* g3  = (const float*)d_in[19];
  const float* bb3 = (const float*)d_in[20];
  float* out = (float*)d_out;

  const int Nn = in_sizes[0] / 256;  // 50000
  const int E  = in_sizes[1];        // 400000
  const int Etot = E + Nn;

  char* ws = (char*)d_ws;
  size_t off = 0;
  auto alloc = [&](size_t bytes) -> char* {
    char* p = ws + off;
    off += (bytes + 255) & ~(size_t)255;
    return p;
  };
  // small buffers
  int* cnt        = (int*)alloc((size_t)(Nn + 1) * 4);
  int* cur        = (int*)alloc((size_t)(Nn + 1) * 4);
  int* row_ptr    = (int*)alloc((size_t)(Nn + 1) * 4);
  int* src_sorted = (int*)alloc((size_t)Etot * 4);
  float* sd1   = (float*)alloc((size_t)Nn * 16 * 4);   // s(0..3), d(4..7)
  float* s2    = (float*)alloc((size_t)Nn * 4 * 4);
  float* d2    = (float*)alloc((size_t)Nn * 4 * 4);
  float* s3    = (float*)alloc((size_t)Nn * 4);
  float* d3    = (float*)alloc((size_t)Nn * 4);
  float* invd3 = (float*)alloc((size_t)Nn * 4);
  float* p3    = (float*)alloc((size_t)Etot * 4);
  unsigned short* W1b = (unsigned short*)alloc((size_t)1024 * 256 * 2);
  unsigned short* W2b = (unsigned short*)alloc((size_t)512 * 1024 * 2);
  unsigned short* W3b = (unsigned short*)alloc((size_t)32 * 512 * 2);
  unsigned short* Qb  = (unsigned short*)alloc((size_t)16 * 256 * 2);
  unsigned short* h3  = (unsigned short*)alloc((size_t)Nn * 32 * 2);
  // big regions (102.4 MB each) with lifetime-based overlays:
  //   regionA: y -> act1 -> act2
  //   regionB: xb -> z1 -> h2
  unsigned short* regA = (unsigned short*)alloc((size_t)Nn * 1024 * 2);
  unsigned short* regB = (unsigned short*)alloc((size_t)Nn * 1024 * 2);
  unsigned short* y    = regA;
  unsigned short* act1 = regA;
  unsigned short* act2 = regA;
  unsigned short* xb   = regB;
  unsigned short* z1   = regB;
  unsigned short* h2   = regB;

  const int mb = (Nn + 127) / 128;

  // ---- prep: bf16 conversions + Qb ----
  cvt_kernel<<<(Nn * 256 / 8 + 255) / 256, 256, 0, stream>>>(x, xb, Nn * 256 / 8);
  cvt_kernel<<<(1024 * 256 / 8 + 255) / 256, 256, 0, stream>>>(W1, W1b, 1024 * 256 / 8);
  cvt_kernel<<<(512 * 1024 / 8 + 255) / 256, 256, 0, stream>>>(W2, W2b, 512 * 1024 / 8);
  cvt_kernel<<<(32 * 512 / 8 + 255) / 256, 256, 0, stream>>>(W3, W3b, 32 * 512 / 8);
  qb_kernel<<<16, 256, 0, stream>>>(W1, as1, ad1, Qb);

  // ---- CSR by dst ----
  hipMemsetAsync(cnt, 0, (size_t)(Nn + 1) * 4, stream);
  int eb = (Etot + 255) / 256;
  hist_kernel<<<eb, 256, 0, stream>>>(edst, cnt, E, Nn);
  scan_kernel<<<1, 1024, 0, stream>>>(cnt, row_ptr, cur, Nn);
  scatter_kernel<<<eb, 256, 0, stream>>>(esrc, edst, cur, src_sorted, E, Nn);

  // ---- layer 1 (input-space aggregation) ----
  gemm_mfma<128, 16, 4, 1, true><<<dim3(mb, 1, 1), 256, 0, stream>>>(
      xb, Qb, sd1, nullptr, Nn, 16, 256, 256, 256, 16, 0, 0, 0, 0);
  aggx_kernel<<<(Nn + 3) / 4, 256, 0, stream>>>(row_ptr, src_sorted, sd1, xb, y, Nn);
  gemm_mfma<128, 128, 2, 2, false><<<dim3(mb, 2, 4), 256, 0, stream>>>(
      y, W1b, z1, b1, Nn, 256, 256, 1024, 256, 1024, 256LL, 256LL * 256, 256LL, 256);
  ln1024_kernel<<<Nn, 256, 0, stream>>>(z1, g1, bb1, act1, Nn);

  // ---- layer 2 ----
  gemm_mfma<128, 128, 2, 2, false><<<dim3(mb, 4, 1), 256, 0, stream>>>(
      act1, W2b, h2, nullptr, Nn, 512, 1024, 1024, 1024, 512, 0, 0, 0, 0);
  sd128_kernel<<<Nn, 256, 0, stream>>>(h2, as2, ad2, s2, d2, Nn);
  agg2m_kernel<<<(Nn + 3) / 4, 256, 0, stream>>>(row_ptr, src_sorted, s2, d2,
                                                 h2, b2, g2, bb2, act2, Nn);

  // ---- layer 3 ----
  gemm_mfma<128, 32, 4, 1, false><<<dim3(mb, 1, 1), 256, 0, stream>>>(
      act2, W3b, h3, nullptr, Nn, 32, 512, 512, 512, 32, 0, 0, 0, 0);
  sd32_kernel<<<(Nn * 32 + 255) / 256, 256, 0, stream>>>(h3, as3, ad3, s3, d3, Nn);
  stats_kernel<<<(Nn + 255) / 256, 256, 0, stream>>>(row_ptr, src_sorted,
                                                     s3, d3, p3, invd3, Nn);
  final_kernel<<<(Nn * 32 + 255) / 256, 256, 0, stream>>>(row_ptr, src_sorted,
      p3, invd3, h3, b3, g3, bb3, out, Nn);
}

// Round 4
// 689.609 us; speedup vs baseline: 2.4279x; 1.1336x over previous
//
#include <hip/hip_runtime.h>
#include <math.h>

// ---------------------------------------------------------------------------
// GAT 3-layer forward, MI355X. Round 4:
//  - Parallel 3-kernel prefix scan (was: 108us single-block serial scan).
//  - GEMM grid-swap (swapxy): N-index fastest so blocks sharing an A tile
//    are dispatch-adjacent -> A fetched from HBM once (was 2-4x re-fetch,
//    ~600MB/launch of avoidable HBM traffic).
//  - Everything else unchanged from round 3.
// ---------------------------------------------------------------------------

#define NEG_ATT 0.2f
#define NEG_ACT 0.01f

typedef __attribute__((ext_vector_type(8))) short bf16x8;
typedef __attribute__((ext_vector_type(8))) unsigned short u16x8;
typedef __attribute__((ext_vector_type(4))) float f32x4;

__device__ __forceinline__ float bf2f(unsigned short u) {
  union { unsigned int i; float f; } c; c.i = ((unsigned int)u) << 16; return c.f;
}
__device__ __forceinline__ unsigned short f2bf(float f) {
  union { float f; unsigned int i; } c; c.f = f;
  unsigned int r = c.i + 0x7FFFu + ((c.i >> 16) & 1u);
  return (unsigned short)(r >> 16);
}

// ---------------------------------------------------------------------------
// f32 -> bf16 bulk convert (n divisible by 8)
// ---------------------------------------------------------------------------
__global__ void cvt_kernel(const float* __restrict__ in,
                           unsigned short* __restrict__ out, int n8) {
  int i = blockIdx.x * 256 + threadIdx.x;
  if (i >= n8) return;
  float4 v0 = reinterpret_cast<const float4*>(in)[i * 2];
  float4 v1 = reinterpret_cast<const float4*>(in)[i * 2 + 1];
  ushort4 o0 = make_ushort4(f2bf(v0.x), f2bf(v0.y), f2bf(v0.z), f2bf(v0.w));
  ushort4 o1 = make_ushort4(f2bf(v1.x), f2bf(v1.y), f2bf(v1.z), f2bf(v1.w));
  reinterpret_cast<ushort4*>(out)[i * 2] = o0;
  reinterpret_cast<ushort4*>(out)[i * 2 + 1] = o1;
}

// ---------------------------------------------------------------------------
// Qb[16][256] bf16: rows 0..3 = W1_h^T a_src,h ; rows 4..7 = W1_h^T a_dst,h ;
// rows 8..15 zero (MFMA N-pad).
// ---------------------------------------------------------------------------
__global__ __launch_bounds__(256) void qb_kernel(const float* __restrict__ W1,
    const float* __restrict__ as1, const float* __restrict__ ad1,
    unsigned short* __restrict__ Qb) {
  int r = blockIdx.x;          // output row
  int k = threadIdx.x;         // 0..255
  if (r >= 8) { Qb[r * 256 + k] = 0; return; }
  int h = r & 3;
  const float* av = (r >> 2) ? ad1 : as1;
  float acc = 0.f;
#pragma unroll 8
  for (int c = 0; c < 256; c++)
    acc += W1[((size_t)(h * 256 + c)) * 256 + k] * av[h * 256 + c];
  Qb[r * 256 + k] = f2bf(acc);
}

// ---------------------------------------------------------------------------
// CSR build: histogram -> parallel 3-kernel exclusive scan -> scatter
// ---------------------------------------------------------------------------
__global__ void hist_kernel(const int* __restrict__ edge_dst,
                            int* __restrict__ cnt, int E, int N) {
  int e = blockIdx.x * 256 + threadIdx.x;
  if (e >= E + N) return;
  int dn = (e < E) ? edge_dst[e] : (e - E);   // self-loops appended
  atomicAdd(&cnt[dn], 1);
}

// scan stage 1: per-block (256-elem chunk) sums
__global__ __launch_bounds__(256) void scan1_kernel(
    const int* __restrict__ cnt, int* __restrict__ bsum, int N) {
  __shared__ int sd_[256];
  int i = blockIdx.x * 256 + threadIdx.x;
  int v = (i < N) ? cnt[i] : 0;
  sd_[threadIdx.x] = v;
  __syncthreads();
#pragma unroll
  for (int off = 128; off; off >>= 1) {
    if (threadIdx.x < off) sd_[threadIdx.x] += sd_[threadIdx.x + off];
    __syncthreads();
  }
  if (threadIdx.x == 0) bsum[blockIdx.x] = sd_[0];
}

// scan stage 2: one block exclusive-scans the <=256 block sums; also writes
// the grand total to row_ptr[N].
__global__ __launch_bounds__(256) void scan2_kernel(
    const int* __restrict__ bsum, int* __restrict__ boff,
    int* __restrict__ row_ptr, int NB, int N) {
  __shared__ int sd_[256];
  int t = threadIdx.x;
  int v = (t < NB) ? bsum[t] : 0;
  sd_[t] = v;
  __syncthreads();
#pragma unroll
  for (int off = 1; off < 256; off <<= 1) {
    int u = (t >= off) ? sd_[t - off] : 0;
    __syncthreads();
    sd_[t] += u;
    __syncthreads();
  }
  if (t < NB) boff[t] = sd_[t] - v;          // exclusive
  if (t == 255) row_ptr[N] = sd_[255];       // total
}

// scan stage 3: per-block exclusive scan + block offset -> row_ptr, cur
__global__ __launch_bounds__(256) void scan3_kernel(
    const int* __restrict__ cnt, const int* __restrict__ boff,
    int* __restrict__ row_ptr, int* __restrict__ cur, int N) {
  __shared__ int sd_[256];
  int t = threadIdx.x;
  int i = blockIdx.x * 256 + t;
  int v = (i < N) ? cnt[i] : 0;
  sd_[t] = v;
  __syncthreads();
#pragma unroll
  for (int off = 1; off < 256; off <<= 1) {
    int u = (t >= off) ? sd_[t - off] : 0;
    __syncthreads();
    sd_[t] += u;
    __syncthreads();
  }
  if (i < N) {
    int val = boff[blockIdx.x] + sd_[t] - v;
    row_ptr[i] = val;
    cur[i] = val;
  }
}

__global__ void scatter_kernel(const int* __restrict__ edge_src,
                               const int* __restrict__ edge_dst,
                               int* __restrict__ cur,
                               int* __restrict__ src_sorted, int E, int N) {
  int e = blockIdx.x * 256 + threadIdx.x;
  if (e >= E + N) return;
  int sn, dn;
  if (e < E) { sn = edge_src[e]; dn = edge_dst[e]; }
  else       { sn = dn = e - E; }
  int pos = atomicAdd(&cur[dn], 1);
  src_sorted[pos] = sn;
}

// ---------------------------------------------------------------------------
// MFMA bf16 GEMM: C[m][n] = sum_k A[m][k]*B[n][k] (+ bias[n]).
// swapxy: M-block index taken from blockIdx.y (N fastest) so blocks sharing
// an A tile are dispatch-adjacent -> A tile HBM-fetched once.
// ---------------------------------------------------------------------------
#define GLOBAL_AS __attribute__((address_space(1)))
#define LDS_AS __attribute__((address_space(3)))

__device__ __forceinline__ void gload_lds16(const void* g, void* l) {
  __builtin_amdgcn_global_load_lds((const GLOBAL_AS unsigned int*)g,
                                   (LDS_AS unsigned int*)l, 16, 0, 0);
}

template <int BM, int BN, int WM, int WN, bool F32OUT, bool SWAPXY>
__global__ __launch_bounds__(256) void gemm_mfma(
    const unsigned short* __restrict__ A, const unsigned short* __restrict__ B,
    void* __restrict__ Cv, const float* __restrict__ bias,
    int M, int N, int K, int lda, int ldb, int ldc,
    long long aZ, long long bZ, long long cZ, int biasZ) {
  constexpr int BK = 64;
  constexpr int FM = BM / (WM * 16);
  constexpr int FN = BN / (WN * 16);
  A += (size_t)blockIdx.z * aZ;
  B += (size_t)blockIdx.z * bZ;
  const size_t cbase = (size_t)blockIdx.z * cZ;
  __shared__ unsigned short As[BM * BK];
  __shared__ unsigned short Bs[BN * BK];
  const int tid = threadIdx.x;
  const int w = tid >> 6, lane = tid & 63;
  const int wm = w / WN, wn = w % WN;
  const int bm = (SWAPXY ? blockIdx.y : blockIdx.x) * BM;
  const int bn = (SWAPXY ? blockIdx.x : blockIdx.y) * BN;
  const int l15 = lane & 15, l4 = lane >> 4;

  f32x4 acc[FM][FN] = {};

  constexpr int CHA = BM * BK / 8;   // 16B chunks in A tile
  constexpr int CHB = BN * BK / 8;

  for (int k0 = 0; k0 < K; k0 += BK) {
#pragma unroll
    for (int c0 = 0; c0 < CHA; c0 += 256) {
      int c = c0 + tid;
      if (CHA - c0 >= 256 || tid < CHA - c0) {
        int cl = c ^ ((c >> 3) & 7);
        int row = cl >> 3;
        int kk = (cl & 7) * 8;
        int gr = bm + row; if (gr > M - 1) gr = M - 1;
        gload_lds16(A + (size_t)gr * lda + k0 + kk,
                    As + (size_t)(c0 + (tid & ~63)) * 8);
      }
    }
#pragma unroll
    for (int c0 = 0; c0 < CHB; c0 += 256) {
      int c = c0 + tid;
      if (CHB - c0 >= 256 || tid < CHB - c0) {
        int cl = c ^ ((c >> 3) & 7);
        int row = cl >> 3;
        int kk = (cl & 7) * 8;
        gload_lds16(B + (size_t)(bn + row) * ldb + k0 + kk,
                    Bs + (size_t)(c0 + (tid & ~63)) * 8);
      }
    }
    __syncthreads();
#pragma unroll
    for (int ks = 0; ks < 2; ks++) {
      bf16x8 af[FM], bfr[FN];
#pragma unroll
      for (int i = 0; i < FM; i++) {
        int row = wm * (FM * 16) + i * 16 + l15;
        int byte = row * (BK * 2) + ks * 64 + l4 * 16;
        byte ^= ((byte >> 7) & 7) << 4;
        af[i] = *reinterpret_cast<const bf16x8*>((const char*)As + byte);
      }
#pragma unroll
      for (int i = 0; i < FN; i++) {
        int row = wn * (FN * 16) + i * 16 + l15;
        int byte = row * (BK * 2) + ks * 64 + l4 * 16;
        byte ^= ((byte >> 7) & 7) << 4;
        bfr[i] = *reinterpret_cast<const bf16x8*>((const char*)Bs + byte);
      }
#pragma unroll
      for (int i = 0; i < FM; i++)
#pragma unroll
        for (int jn = 0; jn < FN; jn++)
          acc[i][jn] = __builtin_amdgcn_mfma_f32_16x16x32_bf16(
              af[i], bfr[jn], acc[i][jn], 0, 0, 0);
    }
    __syncthreads();
  }
  // epilogue: D col = lane&15, row = (lane>>4)*4 + reg (HW-verified)
#pragma unroll
  for (int i = 0; i < FM; i++) {
#pragma unroll
    for (int jn = 0; jn < FN; jn++) {
      int col = bn + wn * (FN * 16) + jn * 16 + l15;
      float bv = bias ? bias[biasZ * blockIdx.z + col] : 0.f;
#pragma unroll
      for (int r = 0; r < 4; r++) {
        int m = bm + wm * (FM * 16) + i * 16 + l4 * 4 + r;
        if (m < M) {
          float val = acc[i][jn][r] + bv;
          if constexpr (F32OUT)
            ((float*)Cv)[cbase + (size_t)m * ldc + col] = val;
          else
            ((unsigned short*)Cv)[cbase + (size_t)m * ldc + col] = f2bf(val);
        }
      }
    }
  }
}

// ---------------------------------------------------------------------------
// Layer-1 fused softmax + INPUT-space aggregation.
// sd1[n][0..3]=s heads, [4..7]=d heads (f32, from the Qb GEMM).
// One wave per node (4 nodes/block). 3 passes over edges: max, den, acc.
// ---------------------------------------------------------------------------
__global__ __launch_bounds__(256) void aggx_kernel(
    const int* __restrict__ row_ptr, const int* __restrict__ src_sorted,
    const float* __restrict__ sd1, const unsigned short* __restrict__ xb,
    unsigned short* __restrict__ y, int N) {
  __shared__ float alds[4][2][64][4];
  int w = threadIdx.x >> 6, lane = threadIdx.x & 63;
  int n = blockIdx.x * 4 + w;
  if (n >= N) return;
  int beg = row_ptr[n], end = row_ptr[n + 1];
  float4 dv = *reinterpret_cast<const float4*>(sd1 + (size_t)n * 16 + 4);

  auto compE = [&](int t, float e[4]) {
    if (t < end) {
      int sj = src_sorted[t];
      float4 sv = *reinterpret_cast<const float4*>(sd1 + (size_t)sj * 16);
      e[0] = sv.x + dv.x; e[1] = sv.y + dv.y;
      e[2] = sv.z + dv.z; e[3] = sv.w + dv.w;
#pragma unroll
      for (int h = 0; h < 4; h++) e[h] = e[h] > 0.f ? e[h] : NEG_ATT * e[h];
    } else {
      e[0] = e[1] = e[2] = e[3] = -1e30f;
    }
  };

  float mx[4] = {-1e30f, -1e30f, -1e30f, -1e30f};
  for (int cb = beg; cb < end; cb += 64) {
    float e[4]; compE(cb + lane, e);
#pragma unroll
    for (int h = 0; h < 4; h++) {
      float m = e[h];
#pragma unroll
      for (int o = 32; o; o >>= 1) m = fmaxf(m, __shfl_xor(m, o));
      mx[h] = fmaxf(mx[h], m);
    }
  }
  float den[4] = {0.f, 0.f, 0.f, 0.f};
  for (int cb = beg; cb < end; cb += 64) {
    float e[4]; compE(cb + lane, e);
#pragma unroll
    for (int h = 0; h < 4; h++) {
      float p = __expf(e[h] - mx[h]);
#pragma unroll
      for (int o = 32; o; o >>= 1) p += __shfl_xor(p, o);
      den[h] += p;
    }
  }
  float ia[4];
#pragma unroll
  for (int h = 0; h < 4; h++) ia[h] = 1.0f / (den[h] + 1e-16f);

  float acc[4][4] = {};
  for (int cb = beg; cb < end; cb += 64) {
    float e[4]; compE(cb + lane, e);
    int pb = ((cb - beg) >> 6) & 1;
    float4 al;
    al.x = __expf(e[0] - mx[0]) * ia[0];
    al.y = __expf(e[1] - mx[1]) * ia[1];
    al.z = __expf(e[2] - mx[2]) * ia[2];
    al.w = __expf(e[3] - mx[3]) * ia[3];
    *reinterpret_cast<float4*>(alds[w][pb][lane]) = al;
    int cd = end - cb; if (cd > 64) cd = 64;
    for (int j = 0; j < cd; j++) {
      float4 a4 = *reinterpret_cast<const float4*>(alds[w][pb][j]);
      int sj = src_sorted[cb + j];
      ushort4 xv = *reinterpret_cast<const ushort4*>(
          xb + (size_t)sj * 256 + lane * 4);
      float x0 = bf2f(xv.x), x1 = bf2f(xv.y), x2 = bf2f(xv.z), x3 = bf2f(xv.w);
      float ar[4] = {a4.x, a4.y, a4.z, a4.w};
#pragma unroll
      for (int h = 0; h < 4; h++) {
        acc[h][0] = fmaf(ar[h], x0, acc[h][0]);
        acc[h][1] = fmaf(ar[h], x1, acc[h][1]);
        acc[h][2] = fmaf(ar[h], x2, acc[h][2]);
        acc[h][3] = fmaf(ar[h], x3, acc[h][3]);
      }
    }
  }
#pragma unroll
  for (int h = 0; h < 4; h++) {
    ushort4 o = make_ushort4(f2bf(acc[h][0]), f2bf(acc[h][1]),
                             f2bf(acc[h][2]), f2bf(acc[h][3]));
    *reinterpret_cast<ushort4*>(y + (size_t)n * 1024 + h * 256 + lane * 4) = o;
  }
}

// ---------------------------------------------------------------------------
// Layer-2 fused softmax + aggregation + bias + LN(512) + leaky_relu.
// ---------------------------------------------------------------------------
__global__ __launch_bounds__(256) void agg2m_kernel(
    const int* __restrict__ row_ptr, const int* __restrict__ src_sorted,
    const float* __restrict__ s2, const float* __restrict__ d2,
    const unsigned short* __restrict__ h2, const float* __restrict__ bias,
    const float* __restrict__ ln_g, const float* __restrict__ ln_b,
    unsigned short* __restrict__ outb, int N) {
  __shared__ float alds[4][2][64][4];
  int w = threadIdx.x >> 6, lane = threadIdx.x & 63;
  int n = blockIdx.x * 4 + w;
  if (n >= N) return;
  int beg = row_ptr[n], end = row_ptr[n + 1];
  int head = lane >> 4, c0 = lane * 8;
  float4 dv = *reinterpret_cast<const float4*>(d2 + (size_t)n * 4);

  auto compE = [&](int t, float e[4]) {
    if (t < end) {
      int sj = src_sorted[t];
      float4 sv = *reinterpret_cast<const float4*>(s2 + (size_t)sj * 4);
      e[0] = sv.x + dv.x; e[1] = sv.y + dv.y;
      e[2] = sv.z + dv.z; e[3] = sv.w + dv.w;
#pragma unroll
      for (int h = 0; h < 4; h++) e[h] = e[h] > 0.f ? e[h] : NEG_ATT * e[h];
    } else {
      e[0] = e[1] = e[2] = e[3] = -1e30f;
    }
  };

  float mx[4] = {-1e30f, -1e30f, -1e30f, -1e30f};
  for (int cb = beg; cb < end; cb += 64) {
    float e[4]; compE(cb + lane, e);
#pragma unroll
    for (int h = 0; h < 4; h++) {
      float m = e[h];
#pragma unroll
      for (int o = 32; o; o >>= 1) m = fmaxf(m, __shfl_xor(m, o));
      mx[h] = fmaxf(mx[h], m);
    }
  }
  float den[4] = {0.f, 0.f, 0.f, 0.f};
  for (int cb = beg; cb < end; cb += 64) {
    float e[4]; compE(cb + lane, e);
#pragma unroll
    for (int h = 0; h < 4; h++) {
      float p = __expf(e[h] - mx[h]);
#pragma unroll
      for (int o = 32; o; o >>= 1) p += __shfl_xor(p, o);
      den[h] += p;
    }
  }
  float ia[4];
#pragma unroll
  for (int h = 0; h < 4; h++) ia[h] = 1.0f / (den[h] + 1e-16f);

  float acc[8] = {};
  for (int cb = beg; cb < end; cb += 64) {
    float e[4]; compE(cb + lane, e);
    int pb = ((cb - beg) >> 6) & 1;
    float4 al;
    al.x = __expf(e[0] - mx[0]) * ia[0];
    al.y = __expf(e[1] - mx[1]) * ia[1];
    al.z = __expf(e[2] - mx[2]) * ia[2];
    al.w = __expf(e[3] - mx[3]) * ia[3];
    *reinterpret_cast<float4*>(alds[w][pb][lane]) = al;
    int cd = end - cb; if (cd > 64) cd = 64;
    for (int j = 0; j < cd; j++) {
      float a = alds[w][pb][j][head];
      int sj = src_sorted[cb + j];
      u16x8 xv = *reinterpret_cast<const u16x8*>(h2 + (size_t)sj * 512 + c0);
#pragma unroll
      for (int i = 0; i < 8; i++)
        acc[i] = fmaf(a, bf2f(xv[i]), acc[i]);
    }
  }
  float v[8], s1 = 0.f, sq = 0.f;
#pragma unroll
  for (int i = 0; i < 8; i++) {
    v[i] = acc[i] + bias[c0 + i];
    s1 += v[i]; sq += v[i] * v[i];
  }
#pragma unroll
  for (int o = 32; o; o >>= 1) { s1 += __shfl_xor(s1, o); sq += __shfl_xor(sq, o); }
  float mean = s1 * (1.0f / 512.0f);
  float var = sq * (1.0f / 512.0f) - mean * mean;
  float rstd = rsqrtf(var + 1e-5f);
  u16x8 ov;
#pragma unroll
  for (int i = 0; i < 8; i++) {
    float yv = (v[i] - mean) * rstd * ln_g[c0 + i] + ln_b[c0 + i];
    yv = yv > 0.f ? yv : NEG_ACT * yv;
    ov[i] = f2bf(yv);
  }
  *reinterpret_cast<u16x8*>(outb + (size_t)n * 512 + c0) = ov;
}

// ---------------------------------------------------------------------------
// LN(1024) + leaky over z1 -> act1 (bias folded into GEMM epilogue).
// ---------------------------------------------------------------------------
__global__ __launch_bounds__(256) void ln1024_kernel(
    const unsigned short* __restrict__ z, const float* __restrict__ ln_g,
    const float* __restrict__ ln_b, unsigned short* __restrict__ outb, int N) {
  int n = blockIdx.x;
  int tid = threadIdx.x;
  int c0 = tid * 4;
  ushort4 zv = *reinterpret_cast<const ushort4*>(z + (size_t)n * 1024 + c0);
  float v[4] = {bf2f(zv.x), bf2f(zv.y), bf2f(zv.z), bf2f(zv.w)};
  float s1 = v[0] + v[1] + v[2] + v[3];
  float sq = v[0]*v[0] + v[1]*v[1] + v[2]*v[2] + v[3]*v[3];
#pragma unroll
  for (int o = 32; o; o >>= 1) { s1 += __shfl_down(s1, o); sq += __shfl_down(sq, o); }
  __shared__ float r1[4], r2[4];
  int wave = tid >> 6, lane = tid & 63;
  if (lane == 0) { r1[wave] = s1; r2[wave] = sq; }
  __syncthreads();
  float t1 = r1[0] + r1[1] + r1[2] + r1[3];
  float t2 = r2[0] + r2[1] + r2[2] + r2[3];
  float mean = t1 * (1.0f / 1024.0f);
  float var = t2 * (1.0f / 1024.0f) - mean * mean;
  float rstd = rsqrtf(var + 1e-5f);
  ushort4 ov;
  float y0 = (v[0] - mean) * rstd * ln_g[c0 + 0] + ln_b[c0 + 0];
  float y1 = (v[1] - mean) * rstd * ln_g[c0 + 1] + ln_b[c0 + 1];
  float y2 = (v[2] - mean) * rstd * ln_g[c0 + 2] + ln_b[c0 + 2];
  float y3 = (v[3] - mean) * rstd * ln_g[c0 + 3] + ln_b[c0 + 3];
  ov.x = f2bf(y0 > 0.f ? y0 : NEG_ACT * y0);
  ov.y = f2bf(y1 > 0.f ? y1 : NEG_ACT * y1);
  ov.z = f2bf(y2 > 0.f ? y2 : NEG_ACT * y2);
  ov.w = f2bf(y3 > 0.f ? y3 : NEG_ACT * y3);
  *reinterpret_cast<ushort4*>(outb + (size_t)n * 1024 + c0) = ov;
}

// ---------------------------------------------------------------------------
// s/d for layer 2 (H=4, C=128): one block per node, one wave per head.
// ---------------------------------------------------------------------------
__global__ __launch_bounds__(256) void sd128_kernel(
    const unsigned short* __restrict__ h, const float* __restrict__ a_src,
    const float* __restrict__ a_dst, float* __restrict__ s,
    float* __restrict__ d, int N) {
  int n = blockIdx.x;
  int head = threadIdx.x >> 6;
  int lane = threadIdx.x & 63;
  const unsigned short* row = h + (size_t)n * 512 + head * 128 + lane * 2;
  ushort2 u = *reinterpret_cast<const ushort2*>(row);
  float2 a = *reinterpret_cast<const float2*>(a_src + head * 128 + lane * 2);
  float2 b = *reinterpret_cast<const float2*>(a_dst + head * 128 + lane * 2);
  float ss = bf2f(u.x) * a.x + bf2f(u.y) * a.y;
  float dd = bf2f(u.x) * b.x + bf2f(u.y) * b.y;
#pragma unroll
  for (int o = 32; o; o >>= 1) { ss += __shfl_down(ss, o); dd += __shfl_down(dd, o); }
  if (lane == 0) { s[(size_t)n * 4 + head] = ss; d[(size_t)n * 4 + head] = dd; }
}

// layer 3: H=1, C=32
__global__ __launch_bounds__(256) void sd32_kernel(
    const unsigned short* __restrict__ h, const float* __restrict__ a_src,
    const float* __restrict__ a_dst, float* __restrict__ s,
    float* __restrict__ d, int N) {
  int idx = blockIdx.x * 256 + threadIdx.x;
  int n = idx >> 5, c = idx & 31;
  if (n >= N) return;
  float v = bf2f(h[(size_t)n * 32 + c]);
  float ss = v * a_src[c], dd = v * a_dst[c];
#pragma unroll
  for (int o = 16; o; o >>= 1) { ss += __shfl_xor(ss, o, 32); dd += __shfl_xor(dd, o, 32); }
  if (c == 0) { s[n] = ss; d[n] = dd; }
}

// ---------------------------------------------------------------------------
// Layer-3 softmax stats (H=1).
// ---------------------------------------------------------------------------
__global__ void stats_kernel(const int* __restrict__ row_ptr,
    const int* __restrict__ src_sorted, const float* __restrict__ s,
    const float* __restrict__ d, float* __restrict__ p_sorted,
    float* __restrict__ inv_den, int N) {
  int idx = blockIdx.x * blockDim.x + threadIdx.x;
  if (idx >= N) return;
  int n = idx;
  int beg = row_ptr[n], end = row_ptr[n + 1];
  float dn = d[n];
  float mx = -1e30f;
  for (int j = beg; j < end; j++) {
    float v = s[src_sorted[j]] + dn;
    v = v > 0.f ? v : NEG_ATT * v;
    mx = fmaxf(mx, v);
  }
  float den = 0.f;
  for (int j = beg; j < end; j++) {
    float v = s[src_sorted[j]] + dn;
    v = v > 0.f ? v : NEG_ATT * v;
    float p = __expf(v - mx);
    p_sorted[j] = p;
    den += p;
  }
  inv_den[n] = 1.0f / (den + 1e-16f);
}

// ---------------------------------------------------------------------------
// Layer-3 aggregation + bias + LN(32) + log_softmax(32) -> f32 output.
// ---------------------------------------------------------------------------
__global__ __launch_bounds__(256) void final_kernel(
    const int* __restrict__ row_ptr, const int* __restrict__ src_sorted,
    const float* __restrict__ p_sorted, const float* __restrict__ inv_den,
    const unsigned short* __restrict__ h3, const float* __restrict__ b3,
    const float* __restrict__ g3, const float* __restrict__ bb3,
    float* __restrict__ out, int N) {
  int idx = blockIdx.x * 256 + threadIdx.x;
  int n = idx >> 5, c = idx & 31;
  if (n >= N) return;
  int beg = row_ptr[n], end = row_ptr[n + 1];
  float acc = 0.f;
  for (int j = beg; j < end; j++)
    acc = fmaf(p_sorted[j], bf2f(h3[(size_t)src_sorted[j] * 32 + c]), acc);
  float v = acc * inv_den[n] + b3[c];
  float s1 = v, s2 = v * v;
#pragma unroll
  for (int o = 16; o; o >>= 1) { s1 += __shfl_xor(s1, o, 32); s2 += __shfl_xor(s2, o, 32); }
  float mean = s1 * (1.f / 32.f), var = s2 * (1.f / 32.f) - mean * mean;
  float y = (v - mean) * rsqrtf(var + 1e-5f) * g3[c] + bb3[c];
  float mx = y;
#pragma unroll
  for (int o = 16; o; o >>= 1) mx = fmaxf(mx, __shfl_xor(mx, o, 32));
  float ex = __expf(y - mx), se = ex;
#pragma unroll
  for (int o = 16; o; o >>= 1) se += __shfl_xor(se, o, 32);
  out[(size_t)n * 32 + c] = y - mx - __logf(se);
}

// ---------------------------------------------------------------------------
extern "C" void kernel_launch(void* const* d_in, const int* in_sizes, int n_in,
                              void* d_out, int out_size, void* d_ws,
                              size_t ws_size, hipStream_t stream) {
  const float* x   = (const float*)d_in[0];
  const int* esrc  = (const int*)d_in[1];
  const int* edst  = (const int*)d_in[2];
  const float* W1  = (const float*)d_in[3];
  const float* as1 = (const float*)d_in[4];
  const float* ad1 = (const float*)d_in[5];
  const float* b1  = (const float*)d_in[6];
  const float* g1  = (const float*)d_in[7];
  const float* bb1 = (const float*)d_in[8];
  const float* W2  = (const float*)d_in[9];
  const float* as2 = (const float*)d_in[10];
  const float* ad2 = (const float*)d_in[11];
  const float* b2  = (const float*)d_in[12];
  const float* g2  = (const float*)d_in[13];
  const float* bb2 = (const float*)d_in[14];
  const float* W3  = (const float*)d_in[15];
  const float* as3 = (const float*)d_in[16];
  const float* ad3 = (const float*)d_in[17];
  const float* b3  = (const float*)d_in[18];
  const float* g3  = (const float*)d_in[19];
  const float* bb3 = (const float*)d_in[20];
  float* out = (float*)d_out;

  const int Nn = in_sizes[0] / 256;  // 50000
  const int E  = in_sizes[1];        // 400000
  const int Etot = E + Nn;
  const int NB = (Nn + 255) / 256;   // 196 scan blocks (<=256 required)

  char* ws = (char*)d_ws;
  size_t off = 0;
  auto alloc = [&](size_t bytes) -> char* {
    char* p = ws + off;
    off += (bytes + 255) & ~(size_t)255;
    return p;
  };
  // small buffers
  int* cnt        = (int*)alloc((size_t)(Nn + 1) * 4);
  int* cur        = (int*)alloc((size_t)(Nn + 1) * 4);
  int* row_ptr    = (int*)alloc((size_t)(Nn + 1) * 4);
  int* bsum       = (int*)alloc(256 * 4);
  int* boff       = (int*)alloc(256 * 4);
  int* src_sorted = (int*)alloc((size_t)Etot * 4);
  float* sd1   = (float*)alloc((size_t)Nn * 16 * 4);   // s(0..3), d(4..7)
  float* s2    = (float*)alloc((size_t)Nn * 4 * 4);
  float* d2    = (float*)alloc((size_t)Nn * 4 * 4);
  float* s3    = (float*)alloc((size_t)Nn * 4);
  float* d3    = (float*)alloc((size_t)Nn * 4);
  float* invd3 = (float*)alloc((size_t)Nn * 4);
  float* p3    = (float*)alloc((size_t)Etot * 4);
  unsigned short* W1b = (unsigned short*)alloc((size_t)1024 * 256 * 2);
  unsigned short* W2b = (unsigned short*)alloc((size_t)512 * 1024 * 2);
  unsigned short* W3b = (unsigned short*)alloc((size_t)32 * 512 * 2);
  unsigned short* Qb  = (unsigned short*)alloc((size_t)16 * 256 * 2);
  unsigned short* h3  = (unsigned short*)alloc((size_t)Nn * 32 * 2);
  // big regions (102.4 MB each) with lifetime-based overlays:
  //   regionA: y -> act1 -> act2
  //   regionB: xb -> z1 -> h2
  unsigned short* regA = (unsigned short*)alloc((size_t)Nn * 1024 * 2);
  unsigned short* regB = (unsigned short*)alloc((size_t)Nn * 1024 * 2);
  unsigned short* y    = regA;
  unsigned short* act1 = regA;
  unsigned short* act2 = regA;
  unsigned short* xb   = regB;
  unsigned short* z1   = regB;
  unsigned short* h2   = regB;

  const int mb = (Nn + 127) / 128;

  // ---- prep: bf16 conversions + Qb ----
  cvt_kernel<<<(Nn * 256 / 8 + 255) / 256, 256, 0, stream>>>(x, xb, Nn * 256 / 8);
  cvt_kernel<<<(1024 * 256 / 8 + 255) / 256, 256, 0, stream>>>(W1, W1b, 1024 * 256 / 8);
  cvt_kernel<<<(512 * 1024 / 8 + 255) / 256, 256, 0, stream>>>(W2, W2b, 512 * 1024 / 8);
  cvt_kernel<<<(32 * 512 / 8 + 255) / 256, 256, 0, stream>>>(W3, W3b, 32 * 512 / 8);
  qb_kernel<<<16, 256, 0, stream>>>(W1, as1, ad1, Qb);

  // ---- CSR by dst (parallel scan) ----
  hipMemsetAsync(cnt, 0, (size_t)(Nn + 1) * 4, stream);
  int eb = (Etot + 255) / 256;
  hist_kernel<<<eb, 256, 0, stream>>>(edst, cnt, E, Nn);
  scan1_kernel<<<NB, 256, 0, stream>>>(cnt, bsum, Nn);
  scan2_kernel<<<1, 256, 0, stream>>>(bsum, boff, row_ptr, NB, Nn);
  scan3_kernel<<<NB, 256, 0, stream>>>(cnt, boff, row_ptr, cur, Nn);
  scatter_kernel<<<eb, 256, 0, stream>>>(esrc, edst, cur, src_sorted, E, Nn);

  // ---- layer 1 (input-space aggregation) ----
  gemm_mfma<128, 16, 4, 1, true, false><<<dim3(mb, 1, 1), 256, 0, stream>>>(
      xb, Qb, sd1, nullptr, Nn, 16, 256, 256, 256, 16, 0, 0, 0, 0);
  aggx_kernel<<<(Nn + 3) / 4, 256, 0, stream>>>(row_ptr, src_sorted, sd1, xb, y, Nn);
  gemm_mfma<128, 128, 2, 2, false, true><<<dim3(2, mb, 4), 256, 0, stream>>>(
      y, W1b, z1, b1, Nn, 256, 256, 1024, 256, 1024, 256LL, 256LL * 256, 256LL, 256);
  ln1024_kernel<<<Nn, 256, 0, stream>>>(z1, g1, bb1, act1, Nn);

  // ---- layer 2 ----
  gemm_mfma<128, 128, 2, 2, false, true><<<dim3(4, mb, 1), 256, 0, stream>>>(
      act1, W2b, h2, nullptr, Nn, 512, 1024, 1024, 1024, 512, 0, 0, 0, 0);
  sd128_kernel<<<Nn, 256, 0, stream>>>(h2, as2, ad2, s2, d2, Nn);
  agg2m_kernel<<<(Nn + 3) / 4, 256, 0, stream>>>(row_ptr, src_sorted, s2, d2,
                                                 h2, b2, g2, bb2, act2, Nn);

  // ---- layer 3 ----
  gemm_mfma<128, 32, 4, 1, false, false><<<dim3(mb, 1, 1), 256, 0, stream>>>(
      act2, W3b, h3, nullptr, Nn, 32, 512, 512, 512, 32, 0, 0, 0, 0);
  sd32_kernel<<<(Nn * 32 + 255) / 256, 256, 0, stream>>>(h3, as3, ad3, s3, d3, Nn);
  stats_kernel<<<(Nn + 255) / 256, 256, 0, stream>>>(row_ptr, src_sorted,
                                                     s3, d3, p3, invd3, Nn);
  final_kernel<<<(Nn * 32 + 255) / 256, 256, 0, stream>>>(row_ptr, src_sorted,
      p3, invd3, h3, b3, g3, bb3, out, Nn);
}

// Round 5
// 682.776 us; speedup vs baseline: 2.4522x; 1.0100x over previous
//
#include <hip/hip_runtime.h>
#include <math.h>

// ---------------------------------------------------------------------------
// GAT 3-layer forward, MI355X. Round 5:
//  - XCD-aware bijective block remap (m204) inside gemm_mfma: each XCD gets
//    contiguous complete m-groups (n fastest, m middle, z slowest), so every
//    A-tile is HBM-fetched once and L2-served to the n-blocks sharing it.
//    (Round 4's swapxy put A-sharing blocks on 4 DIFFERENT XCD L2s.)
//  - Everything else unchanged from round 4.
// ---------------------------------------------------------------------------

#define NEG_ATT 0.2f
#define NEG_ACT 0.01f

typedef __attribute__((ext_vector_type(8))) short bf16x8;
typedef __attribute__((ext_vector_type(8))) unsigned short u16x8;
typedef __attribute__((ext_vector_type(4))) float f32x4;

__device__ __forceinline__ float bf2f(unsigned short u) {
  union { unsigned int i; float f; } c; c.i = ((unsigned int)u) << 16; return c.f;
}
__device__ __forceinline__ unsigned short f2bf(float f) {
  union { float f; unsigned int i; } c; c.f = f;
  unsigned int r = c.i + 0x7FFFu + ((c.i >> 16) & 1u);
  return (unsigned short)(r >> 16);
}

// ---------------------------------------------------------------------------
// f32 -> bf16 bulk convert (n divisible by 8)
// ---------------------------------------------------------------------------
__global__ void cvt_kernel(const float* __restrict__ in,
                           unsigned short* __restrict__ out, int n8) {
  int i = blockIdx.x * 256 + threadIdx.x;
  if (i >= n8) return;
  float4 v0 = reinterpret_cast<const float4*>(in)[i * 2];
  float4 v1 = reinterpret_cast<const float4*>(in)[i * 2 + 1];
  ushort4 o0 = make_ushort4(f2bf(v0.x), f2bf(v0.y), f2bf(v0.z), f2bf(v0.w));
  ushort4 o1 = make_ushort4(f2bf(v1.x), f2bf(v1.y), f2bf(v1.z), f2bf(v1.w));
  reinterpret_cast<ushort4*>(out)[i * 2] = o0;
  reinterpret_cast<ushort4*>(out)[i * 2 + 1] = o1;
}

// ---------------------------------------------------------------------------
// Qb[16][256] bf16: rows 0..3 = W1_h^T a_src,h ; rows 4..7 = W1_h^T a_dst,h ;
// rows 8..15 zero (MFMA N-pad).
// ---------------------------------------------------------------------------
__global__ __launch_bounds__(256) void qb_kernel(const float* __restrict__ W1,
    const float* __restrict__ as1, const float* __restrict__ ad1,
    unsigned short* __restrict__ Qb) {
  int r = blockIdx.x;          // output row
  int k = threadIdx.x;         // 0..255
  if (r >= 8) { Qb[r * 256 + k] = 0; return; }
  int h = r & 3;
  const float* av = (r >> 2) ? ad1 : as1;
  float acc = 0.f;
#pragma unroll 8
  for (int c = 0; c < 256; c++)
    acc += W1[((size_t)(h * 256 + c)) * 256 + k] * av[h * 256 + c];
  Qb[r * 256 + k] = f2bf(acc);
}

// ---------------------------------------------------------------------------
// CSR build: histogram -> parallel 3-kernel exclusive scan -> scatter
// ---------------------------------------------------------------------------
__global__ void hist_kernel(const int* __restrict__ edge_dst,
                            int* __restrict__ cnt, int E, int N) {
  int e = blockIdx.x * 256 + threadIdx.x;
  if (e >= E + N) return;
  int dn = (e < E) ? edge_dst[e] : (e - E);   // self-loops appended
  atomicAdd(&cnt[dn], 1);
}

// scan stage 1: per-block (256-elem chunk) sums
__global__ __launch_bounds__(256) void scan1_kernel(
    const int* __restrict__ cnt, int* __restrict__ bsum, int N) {
  __shared__ int sd_[256];
  int i = blockIdx.x * 256 + threadIdx.x;
  int v = (i < N) ? cnt[i] : 0;
  sd_[threadIdx.x] = v;
  __syncthreads();
#pragma unroll
  for (int off = 128; off; off >>= 1) {
    if (threadIdx.x < off) sd_[threadIdx.x] += sd_[threadIdx.x + off];
    __syncthreads();
  }
  if (threadIdx.x == 0) bsum[blockIdx.x] = sd_[0];
}

// scan stage 2: one block exclusive-scans the <=256 block sums; also writes
// the grand total to row_ptr[N].
__global__ __launch_bounds__(256) void scan2_kernel(
    const int* __restrict__ bsum, int* __restrict__ boff,
    int* __restrict__ row_ptr, int NB, int N) {
  __shared__ int sd_[256];
  int t = threadIdx.x;
  int v = (t < NB) ? bsum[t] : 0;
  sd_[t] = v;
  __syncthreads();
#pragma unroll
  for (int off = 1; off < 256; off <<= 1) {
    int u = (t >= off) ? sd_[t - off] : 0;
    __syncthreads();
    sd_[t] += u;
    __syncthreads();
  }
  if (t < NB) boff[t] = sd_[t] - v;          // exclusive
  if (t == 255) row_ptr[N] = sd_[255];       // total
}

// scan stage 3: per-block exclusive scan + block offset -> row_ptr, cur
__global__ __launch_bounds__(256) void scan3_kernel(
    const int* __restrict__ cnt, const int* __restrict__ boff,
    int* __restrict__ row_ptr, int* __restrict__ cur, int N) {
  __shared__ int sd_[256];
  int t = threadIdx.x;
  int i = blockIdx.x * 256 + t;
  int v = (i < N) ? cnt[i] : 0;
  sd_[t] = v;
  __syncthreads();
#pragma unroll
  for (int off = 1; off < 256; off <<= 1) {
    int u = (t >= off) ? sd_[t - off] : 0;
    __syncthreads();
    sd_[t] += u;
    __syncthreads();
  }
  if (i < N) {
    int val = boff[blockIdx.x] + sd_[t] - v;
    row_ptr[i] = val;
    cur[i] = val;
  }
}

__global__ void scatter_kernel(const int* __restrict__ edge_src,
                               const int* __restrict__ edge_dst,
                               int* __restrict__ cur,
                               int* __restrict__ src_sorted, int E, int N) {
  int e = blockIdx.x * 256 + threadIdx.x;
  if (e >= E + N) return;
  int sn, dn;
  if (e < E) { sn = edge_src[e]; dn = edge_dst[e]; }
  else       { sn = dn = e - E; }
  int pos = atomicAdd(&cur[dn], 1);
  src_sorted[pos] = sn;
}

// ---------------------------------------------------------------------------
// MFMA bf16 GEMM: C[m][n] = sum_k A[m][k]*B[n][k] (+ bias[n]).
// Grid launched as (nx, nm, nz). In-kernel XCD-bijective remap (m204):
// dispatch b lands on XCD b%8; logical tile id ordered n-fastest/m/z so each
// XCD owns contiguous complete m-groups -> A-tile fetched from HBM once.
// ---------------------------------------------------------------------------
#define GLOBAL_AS __attribute__((address_space(1)))
#define LDS_AS __attribute__((address_space(3)))

__device__ __forceinline__ void gload_lds16(const void* g, void* l) {
  __builtin_amdgcn_global_load_lds((const GLOBAL_AS unsigned int*)g,
                                   (LDS_AS unsigned int*)l, 16, 0, 0);
}

template <int BM, int BN, int WM, int WN, bool F32OUT>
__global__ __launch_bounds__(256) void gemm_mfma(
    const unsigned short* __restrict__ A, const unsigned short* __restrict__ B,
    void* __restrict__ Cv, const float* __restrict__ bias,
    int M, int N, int K, int lda, int ldb, int ldc,
    long long aZ, long long bZ, long long cZ, int biasZ) {
  constexpr int BK = 64;
  constexpr int FM = BM / (WM * 16);
  constexpr int FN = BN / (WN * 16);
  // ---- XCD-bijective remap (m204) ----
  const int flat = blockIdx.x + gridDim.x * (blockIdx.y + gridDim.y * blockIdx.z);
  const int nwg = gridDim.x * gridDim.y * gridDim.z;
  const int xcd = flat & 7, slot = flat >> 3;
  const int q = nwg >> 3, r = nwg & 7;
  const int wgid = (xcd < r ? xcd * (q + 1) : r * (q + 1) + (xcd - r) * q) + slot;
  const int nx = gridDim.x;
  const int per_z = nx * gridDim.y;
  const int bz = wgid / per_z;
  const int rem = wgid - bz * per_z;
  const int bmi = rem / nx;
  const int bni = rem - bmi * nx;

  A += (size_t)bz * aZ;
  B += (size_t)bz * bZ;
  const size_t cbase = (size_t)bz * cZ;
  __shared__ unsigned short As[BM * BK];
  __shared__ unsigned short Bs[BN * BK];
  const int tid = threadIdx.x;
  const int w = tid >> 6, lane = tid & 63;
  const int wm = w / WN, wn = w % WN;
  const int bm = bmi * BM;
  const int bn = bni * BN;
  const int l15 = lane & 15, l4 = lane >> 4;

  f32x4 acc[FM][FN] = {};

  constexpr int CHA = BM * BK / 8;   // 16B chunks in A tile
  constexpr int CHB = BN * BK / 8;

  for (int k0 = 0; k0 < K; k0 += BK) {
#pragma unroll
    for (int c0 = 0; c0 < CHA; c0 += 256) {
      int c = c0 + tid;
      if (CHA - c0 >= 256 || tid < CHA - c0) {
        int cl = c ^ ((c >> 3) & 7);
        int row = cl >> 3;
        int kk = (cl & 7) * 8;
        int gr = bm + row; if (gr > M - 1) gr = M - 1;
        gload_lds16(A + (size_t)gr * lda + k0 + kk,
                    As + (size_t)(c0 + (tid & ~63)) * 8);
      }
    }
#pragma unroll
    for (int c0 = 0; c0 < CHB; c0 += 256) {
      int c = c0 + tid;
      if (CHB - c0 >= 256 || tid < CHB - c0) {
        int cl = c ^ ((c >> 3) & 7);
        int row = cl >> 3;
        int kk = (cl & 7) * 8;
        gload_lds16(B + (size_t)(bn + row) * ldb + k0 + kk,
                    Bs + (size_t)(c0 + (tid & ~63)) * 8);
      }
    }
    __syncthreads();
#pragma unroll
    for (int ks = 0; ks < 2; ks++) {
      bf16x8 af[FM], bfr[FN];
#pragma unroll
      for (int i = 0; i < FM; i++) {
        int row = wm * (FM * 16) + i * 16 + l15;
        int byte = row * (BK * 2) + ks * 64 + l4 * 16;
        byte ^= ((byte >> 7) & 7) << 4;
        af[i] = *reinterpret_cast<const bf16x8*>((const char*)As + byte);
      }
#pragma unroll
      for (int i = 0; i < FN; i++) {
        int row = wn * (FN * 16) + i * 16 + l15;
        int byte = row * (BK * 2) + ks * 64 + l4 * 16;
        byte ^= ((byte >> 7) & 7) << 4;
        bfr[i] = *reinterpret_cast<const bf16x8*>((const char*)Bs + byte);
      }
#pragma unroll
      for (int i = 0; i < FM; i++)
#pragma unroll
        for (int jn = 0; jn < FN; jn++)
          acc[i][jn] = __builtin_amdgcn_mfma_f32_16x16x32_bf16(
              af[i], bfr[jn], acc[i][jn], 0, 0, 0);
    }
    __syncthreads();
  }
  // epilogue: D col = lane&15, row = (lane>>4)*4 + reg (HW-verified)
#pragma unroll
  for (int i = 0; i < FM; i++) {
#pragma unroll
    for (int jn = 0; jn < FN; jn++) {
      int col = bn + wn * (FN * 16) + jn * 16 + l15;
      float bv = bias ? bias[biasZ * bz + col] : 0.f;
#pragma unroll
      for (int r2 = 0; r2 < 4; r2++) {
        int m = bm + wm * (FM * 16) + i * 16 + l4 * 4 + r2;
        if (m < M) {
          float val = acc[i][jn][r2] + bv;
          if constexpr (F32OUT)
            ((float*)Cv)[cbase + (size_t)m * ldc + col] = val;
          else
            ((unsigned short*)Cv)[cbase + (size_t)m * ldc + col] = f2bf(val);
        }
      }
    }
  }
}

// ---------------------------------------------------------------------------
// Layer-1 fused softmax + INPUT-space aggregation.
// sd1[n][0..3]=s heads, [4..7]=d heads (f32, from the Qb GEMM).
// One wave per node (4 nodes/block). 3 passes over edges: max, den, acc.
// ---------------------------------------------------------------------------
__global__ __launch_bounds__(256) void aggx_kernel(
    const int* __restrict__ row_ptr, const int* __restrict__ src_sorted,
    const float* __restrict__ sd1, const unsigned short* __restrict__ xb,
    unsigned short* __restrict__ y, int N) {
  __shared__ float alds[4][2][64][4];
  int w = threadIdx.x >> 6, lane = threadIdx.x & 63;
  int n = blockIdx.x * 4 + w;
  if (n >= N) return;
  int beg = row_ptr[n], end = row_ptr[n + 1];
  float4 dv = *reinterpret_cast<const float4*>(sd1 + (size_t)n * 16 + 4);

  auto compE = [&](int t, float e[4]) {
    if (t < end) {
      int sj = src_sorted[t];
      float4 sv = *reinterpret_cast<const float4*>(sd1 + (size_t)sj * 16);
      e[0] = sv.x + dv.x; e[1] = sv.y + dv.y;
      e[2] = sv.z + dv.z; e[3] = sv.w + dv.w;
#pragma unroll
      for (int h = 0; h < 4; h++) e[h] = e[h] > 0.f ? e[h] : NEG_ATT * e[h];
    } else {
      e[0] = e[1] = e[2] = e[3] = -1e30f;
    }
  };

  float mx[4] = {-1e30f, -1e30f, -1e30f, -1e30f};
  for (int cb = beg; cb < end; cb += 64) {
    float e[4]; compE(cb + lane, e);
#pragma unroll
    for (int h = 0; h < 4; h++) {
      float m = e[h];
#pragma unroll
      for (int o = 32; o; o >>= 1) m = fmaxf(m, __shfl_xor(m, o));
      mx[h] = fmaxf(mx[h], m);
    }
  }
  float den[4] = {0.f, 0.f, 0.f, 0.f};
  for (int cb = beg; cb < end; cb += 64) {
    float e[4]; compE(cb + lane, e);
#pragma unroll
    for (int h = 0; h < 4; h++) {
      float p = __expf(e[h] - mx[h]);
#pragma unroll
      for (int o = 32; o; o >>= 1) p += __shfl_xor(p, o);
      den[h] += p;
    }
  }
  float ia[4];
#pragma unroll
  for (int h = 0; h < 4; h++) ia[h] = 1.0f / (den[h] + 1e-16f);

  float acc[4][4] = {};
  for (int cb = beg; cb < end; cb += 64) {
    float e[4]; compE(cb + lane, e);
    int pb = ((cb - beg) >> 6) & 1;
    float4 al;
    al.x = __expf(e[0] - mx[0]) * ia[0];
    al.y = __expf(e[1] - mx[1]) * ia[1];
    al.z = __expf(e[2] - mx[2]) * ia[2];
    al.w = __expf(e[3] - mx[3]) * ia[3];
    *reinterpret_cast<float4*>(alds[w][pb][lane]) = al;
    int cd = end - cb; if (cd > 64) cd = 64;
    for (int j = 0; j < cd; j++) {
      float4 a4 = *reinterpret_cast<const float4*>(alds[w][pb][j]);
      int sj = src_sorted[cb + j];
      ushort4 xv = *reinterpret_cast<const ushort4*>(
          xb + (size_t)sj * 256 + lane * 4);
      float x0 = bf2f(xv.x), x1 = bf2f(xv.y), x2 = bf2f(xv.z), x3 = bf2f(xv.w);
      float ar[4] = {a4.x, a4.y, a4.z, a4.w};
#pragma unroll
      for (int h = 0; h < 4; h++) {
        acc[h][0] = fmaf(ar[h], x0, acc[h][0]);
        acc[h][1] = fmaf(ar[h], x1, acc[h][1]);
        acc[h][2] = fmaf(ar[h], x2, acc[h][2]);
        acc[h][3] = fmaf(ar[h], x3, acc[h][3]);
      }
    }
  }
#pragma unroll
  for (int h = 0; h < 4; h++) {
    ushort4 o = make_ushort4(f2bf(acc[h][0]), f2bf(acc[h][1]),
                             f2bf(acc[h][2]), f2bf(acc[h][3]));
    *reinterpret_cast<ushort4*>(y + (size_t)n * 1024 + h * 256 + lane * 4) = o;
  }
}

// ---------------------------------------------------------------------------
// Layer-2 fused softmax + aggregation + bias + LN(512) + leaky_relu.
// ---------------------------------------------------------------------------
__global__ __launch_bounds__(256) void agg2m_kernel(
    const int* __restrict__ row_ptr, const int* __restrict__ src_sorted,
    const float* __restrict__ s2, const float* __restrict__ d2,
    const unsigned short* __restrict__ h2, const float* __restrict__ bias,
    const float* __restrict__ ln_g, const float* __restrict__ ln_b,
    unsigned short* __restrict__ outb, int N) {
  __shared__ float alds[4][2][64][4];
  int w = threadIdx.x >> 6, lane = threadIdx.x & 63;
  int n = blockIdx.x * 4 + w;
  if (n >= N) return;
  int beg = row_ptr[n], end = row_ptr[n + 1];
  int head = lane >> 4, c0 = lane * 8;
  float4 dv = *reinterpret_cast<const float4*>(d2 + (size_t)n * 4);

  auto compE = [&](int t, float e[4]) {
    if (t < end) {
      int sj = src_sorted[t];
      float4 sv = *reinterpret_cast<const float4*>(s2 + (size_t)sj * 4);
      e[0] = sv.x + dv.x; e[1] = sv.y + dv.y;
      e[2] = sv.z + dv.z; e[3] = sv.w + dv.w;
#pragma unroll
      for (int h = 0; h < 4; h++) e[h] = e[h] > 0.f ? e[h] : NEG_ATT * e[h];
    } else {
      e[0] = e[1] = e[2] = e[3] = -1e30f;
    }
  };

  float mx[4] = {-1e30f, -1e30f, -1e30f, -1e30f};
  for (int cb = beg; cb < end; cb += 64) {
    float e[4]; compE(cb + lane, e);
#pragma unroll
    for (int h = 0; h < 4; h++) {
      float m = e[h];
#pragma unroll
      for (int o = 32; o; o >>= 1) m = fmaxf(m, __shfl_xor(m, o));
      mx[h] = fmaxf(mx[h], m);
    }
  }
  float den[4] = {0.f, 0.f, 0.f, 0.f};
  for (int cb = beg; cb < end; cb += 64) {
    float e[4]; compE(cb + lane, e);
#pragma unroll
    for (int h = 0; h < 4; h++) {
      float p = __expf(e[h] - mx[h]);
#pragma unroll
      for (int o = 32; o; o >>= 1) p += __shfl_xor(p, o);
      den[h] += p;
    }
  }
  float ia[4];
#pragma unroll
  for (int h = 0; h < 4; h++) ia[h] = 1.0f / (den[h] + 1e-16f);

  float acc[8] = {};
  for (int cb = beg; cb < end; cb += 64) {
    float e[4]; compE(cb + lane, e);
    int pb = ((cb - beg) >> 6) & 1;
    float4 al;
    al.x = __expf(e[0] - mx[0]) * ia[0];
    al.y = __expf(e[1] - mx[1]) * ia[1];
    al.z = __expf(e[2] - mx[2]) * ia[2];
    al.w = __expf(e[3] - mx[3]) * ia[3];
    *reinterpret_cast<float4*>(alds[w][pb][lane]) = al;
    int cd = end - cb; if (cd > 64) cd = 64;
    for (int j = 0; j < cd; j++) {
      float a = alds[w][pb][j][head];
      int sj = src_sorted[cb + j];
      u16x8 xv = *reinterpret_cast<const u16x8*>(h2 + (size_t)sj * 512 + c0);
#pragma unroll
      for (int i = 0; i < 8; i++)
        acc[i] = fmaf(a, bf2f(xv[i]), acc[i]);
    }
  }
  float v[8], s1 = 0.f, sq = 0.f;
#pragma unroll
  for (int i = 0; i < 8; i++) {
    v[i] = acc[i] + bias[c0 + i];
    s1 += v[i]; sq += v[i] * v[i];
  }
#pragma unroll
  for (int o = 32; o; o >>= 1) { s1 += __shfl_xor(s1, o); sq += __shfl_xor(sq, o); }
  float mean = s1 * (1.0f / 512.0f);
  float var = sq * (1.0f / 512.0f) - mean * mean;
  float rstd = rsqrtf(var + 1e-5f);
  u16x8 ov;
#pragma unroll
  for (int i = 0; i < 8; i++) {
    float yv = (v[i] - mean) * rstd * ln_g[c0 + i] + ln_b[c0 + i];
    yv = yv > 0.f ? yv : NEG_ACT * yv;
    ov[i] = f2bf(yv);
  }
  *reinterpret_cast<u16x8*>(outb + (size_t)n * 512 + c0) = ov;
}

// ---------------------------------------------------------------------------
// LN(1024) + leaky over z1 -> act1 (bias folded into GEMM epilogue).
// ---------------------------------------------------------------------------
__global__ __launch_bounds__(256) void ln1024_kernel(
    const unsigned short* __restrict__ z, const float* __restrict__ ln_g,
    const float* __restrict__ ln_b, unsigned short* __restrict__ outb, int N) {
  int n = blockIdx.x;
  int tid = threadIdx.x;
  int c0 = tid * 4;
  ushort4 zv = *reinterpret_cast<const ushort4*>(z + (size_t)n * 1024 + c0);
  float v[4] = {bf2f(zv.x), bf2f(zv.y), bf2f(zv.z), bf2f(zv.w)};
  float s1 = v[0] + v[1] + v[2] + v[3];
  float sq = v[0]*v[0] + v[1]*v[1] + v[2]*v[2] + v[3]*v[3];
#pragma unroll
  for (int o = 32; o; o >>= 1) { s1 += __shfl_down(s1, o); sq += __shfl_down(sq, o); }
  __shared__ float r1[4], r2[4];
  int wave = tid >> 6, lane = tid & 63;
  if (lane == 0) { r1[wave] = s1; r2[wave] = sq; }
  __syncthreads();
  float t1 = r1[0] + r1[1] + r1[2] + r1[3];
  float t2 = r2[0] + r2[1] + r2[2] + r2[3];
  float mean = t1 * (1.0f / 1024.0f);
  float var = t2 * (1.0f / 1024.0f) - mean * mean;
  float rstd = rsqrtf(var + 1e-5f);
  ushort4 ov;
  float y0 = (v[0] - mean) * rstd * ln_g[c0 + 0] + ln_b[c0 + 0];
  float y1 = (v[1] - mean) * rstd * ln_g[c0 + 1] + ln_b[c0 + 1];
  float y2 = (v[2] - mean) * rstd * ln_g[c0 + 2] + ln_b[c0 + 2];
  float y3 = (v[3] - mean) * rstd * ln_g[c0 + 3] + ln_b[c0 + 3];
  ov.x = f2bf(y0 > 0.f ? y0 : NEG_ACT * y0);
  ov.y = f2bf(y1 > 0.f ? y1 : NEG_ACT * y1);
  ov.z = f2bf(y2 > 0.f ? y2 : NEG_ACT * y2);
  ov.w = f2bf(y3 > 0.f ? y3 : NEG_ACT * y3);
  *reinterpret_cast<ushort4*>(outb + (size_t)n * 1024 + c0) = ov;
}

// ---------------------------------------------------------------------------
// s/d for layer 2 (H=4, C=128): one block per node, one wave per head.
// ---------------------------------------------------------------------------
__global__ __launch_bounds__(256) void sd128_kernel(
    const unsigned short* __restrict__ h, const float* __restrict__ a_src,
    const float* __restrict__ a_dst, float* __restrict__ s,
    float* __restrict__ d, int N) {
  int n = blockIdx.x;
  int head = threadIdx.x >> 6;
  int lane = threadIdx.x & 63;
  const unsigned short* row = h + (size_t)n * 512 + head * 128 + lane * 2;
  ushort2 u = *reinterpret_cast<const ushort2*>(row);
  float2 a = *reinterpret_cast<const float2*>(a_src + head * 128 + lane * 2);
  float2 b = *reinterpret_cast<const float2*>(a_dst + head * 128 + lane * 2);
  float ss = bf2f(u.x) * a.x + bf2f(u.y) * a.y;
  float dd = bf2f(u.x) * b.x + bf2f(u.y) * b.y;
#pragma unroll
  for (int o = 32; o; o >>= 1) { ss += __shfl_down(ss, o); dd += __shfl_down(dd, o); }
  if (lane == 0) { s[(size_t)n * 4 + head] = ss; d[(size_t)n * 4 + head] = dd; }
}

// layer 3: H=1, C=32
__global__ __launch_bounds__(256) void sd32_kernel(
    const unsigned short* __restrict__ h, const float* __restrict__ a_src,
    const float* __restrict__ a_dst, float* __restrict__ s,
    float* __restrict__ d, int N) {
  int idx = blockIdx.x * 256 + threadIdx.x;
  int n = idx >> 5, c = idx & 31;
  if (n >= N) return;
  float v = bf2f(h[(size_t)n * 32 + c]);
  float ss = v * a_src[c], dd = v * a_dst[c];
#pragma unroll
  for (int o = 16; o; o >>= 1) { ss += __shfl_xor(ss, o, 32); dd += __shfl_xor(dd, o, 32); }
  if (c == 0) { s[n] = ss; d[n] = dd; }
}

// ---------------------------------------------------------------------------
// Layer-3 softmax stats (H=1).
// ---------------------------------------------------------------------------
__global__ void stats_kernel(const int* __restrict__ row_ptr,
    const int* __restrict__ src_sorted, const float* __restrict__ s,
    const float* __restrict__ d, float* __restrict__ p_sorted,
    float* __restrict__ inv_den, int N) {
  int idx = blockIdx.x * blockDim.x + threadIdx.x;
  if (idx >= N) return;
  int n = idx;
  int beg = row_ptr[n], end = row_ptr[n + 1];
  float dn = d[n];
  float mx = -1e30f;
  for (int j = beg; j < end; j++) {
    float v = s[src_sorted[j]] + dn;
    v = v > 0.f ? v : NEG_ATT * v;
    mx = fmaxf(mx, v);
  }
  float den = 0.f;
  for (int j = beg; j < end; j++) {
    float v = s[src_sorted[j]] + dn;
    v = v > 0.f ? v : NEG_ATT * v;
    float p = __expf(v - mx);
    p_sorted[j] = p;
    den += p;
  }
  inv_den[n] = 1.0f / (den + 1e-16f);
}

// ---------------------------------------------------------------------------
// Layer-3 aggregation + bias + LN(32) + log_softmax(32) -> f32 output.
// ---------------------------------------------------------------------------
__global__ __launch_bounds__(256) void final_kernel(
    const int* __restrict__ row_ptr, const int* __restrict__ src_sorted,
    const float* __restrict__ p_sorted, const float* __restrict__ inv_den,
    const unsigned short* __restrict__ h3, const float* __restrict__ b3,
    const float* __restrict__ g3, const float* __restrict__ bb3,
    float* __restrict__ out, int N) {
  int idx = blockIdx.x * 256 + threadIdx.x;
  int n = idx >> 5, c = idx & 31;
  if (n >= N) return;
  int beg = row_ptr[n], end = row_ptr[n + 1];
  float acc = 0.f;
  for (int j = beg; j < end; j++)
    acc = fmaf(p_sorted[j], bf2f(h3[(size_t)src_sorted[j] * 32 + c]), acc);
  float v = acc * inv_den[n] + b3[c];
  float s1 = v, s2 = v * v;
#pragma unroll
  for (int o = 16; o; o >>= 1) { s1 += __shfl_xor(s1, o, 32); s2 += __shfl_xor(s2, o, 32); }
  float mean = s1 * (1.f / 32.f), var = s2 * (1.f / 32.f) - mean * mean;
  float y = (v - mean) * rsqrtf(var + 1e-5f) * g3[c] + bb3[c];
  float mx = y;
#pragma unroll
  for (int o = 16; o; o >>= 1) mx = fmaxf(mx, __shfl_xor(mx, o, 32));
  float ex = __expf(y - mx), se = ex;
#pragma unroll
  for (int o = 16; o; o >>= 1) se += __shfl_xor(se, o, 32);
  out[(size_t)n * 32 + c] = y - mx - __logf(se);
}

// ---------------------------------------------------------------------------
extern "C" void kernel_launch(void* const* d_in, const int* in_sizes, int n_in,
                              void* d_out, int out_size, void* d_ws,
                              size_t ws_size, hipStream_t stream) {
  const float* x   = (const float*)d_in[0];
  const int* esrc  = (const int*)d_in[1];
  const int* edst  = (const int*)d_in[2];
  const float* W1  = (const float*)d_in[3];
  const float* as1 = (const float*)d_in[4];
  const float* ad1 = (const float*)d_in[5];
  const float* b1  = (const float*)d_in[6];
  const float* g1  = (const float*)d_in[7];
  const float* bb1 = (const float*)d_in[8];
  const float* W2  = (const float*)d_in[9];
  const float* as2 = (const float*)d_in[10];
  const float* ad2 = (const float*)d_in[11];
  const float* b2  = (const float*)d_in[12];
  const float* g2  = (const float*)d_in[13];
  const float* bb2 = (const float*)d_in[14];
  const float* W3  = (const float*)d_in[15];
  const float* as3 = (const float*)d_in[16];
  const float* ad3 = (const float*)d_in[17];
  const float* b3  = (const float*)d_in[18];
  const float* g3  = (const float*)d_in[19];
  const float* bb3 = (const float*)d_in[20];
  float* out = (float*)d_out;

  const int Nn = in_sizes[0] / 256;  // 50000
  const int E  = in_sizes[1];        // 400000
  const int Etot = E + Nn;
  const int NB = (Nn + 255) / 256;   // 196 scan blocks (<=256 required)

  char* ws = (char*)d_ws;
  size_t off = 0;
  auto alloc = [&](size_t bytes) -> char* {
    char* p = ws + off;
    off += (bytes + 255) & ~(size_t)255;
    return p;
  };
  // small buffers
  int* cnt        = (int*)alloc((size_t)(Nn + 1) * 4);
  int* cur        = (int*)alloc((size_t)(Nn + 1) * 4);
  int* row_ptr    = (int*)alloc((size_t)(Nn + 1) * 4);
  int* bsum       = (int*)alloc(256 * 4);
  int* boff       = (int*)alloc(256 * 4);
  int* src_sorted = (int*)alloc((size_t)Etot * 4);
  float* sd1   = (float*)alloc((size_t)Nn * 16 * 4);   // s(0..3), d(4..7)
  float* s2    = (float*)alloc((size_t)Nn * 4 * 4);
  float* d2    = (float*)alloc((size_t)Nn * 4 * 4);
  float* s3    = (float*)alloc((size_t)Nn * 4);
  float* d3    = (float*)alloc((size_t)Nn * 4);
  float* invd3 = (float*)alloc((size_t)Nn * 4);
  float* p3    = (float*)alloc((size_t)Etot * 4);
  unsigned short* W1b = (unsigned short*)alloc((size_t)1024 * 256 * 2);
  unsigned short* W2b = (unsigned short*)alloc((size_t)512 * 1024 * 2);
  unsigned short* W3b = (unsigned short*)alloc((size_t)32 * 512 * 2);
  unsigned short* Qb  = (unsigned short*)alloc((size_t)16 * 256 * 2);
  unsigned short* h3  = (unsigned short*)alloc((size_t)Nn * 32 * 2);
  // big regions (102.4 MB each) with lifetime-based overlays:
  //   regionA: y -> act1 -> act2
  //   regionB: xb -> z1 -> h2
  unsigned short* regA = (unsigned short*)alloc((size_t)Nn * 1024 * 2);
  unsigned short* regB = (unsigned short*)alloc((size_t)Nn * 1024 * 2);
  unsigned short* y    = regA;
  unsigned short* act1 = regA;
  unsigned short* act2 = regA;
  unsigned short* xb   = regB;
  unsigned short* z1   = regB;
  unsigned short* h2   = regB;

  const int mb = (Nn + 127) / 128;

  // ---- prep: bf16 conversions + Qb ----
  cvt_kernel<<<(Nn * 256 / 8 + 255) / 256, 256, 0, stream>>>(x, xb, Nn * 256 / 8);
  cvt_kernel<<<(1024 * 256 / 8 + 255) / 256, 256, 0, stream>>>(W1, W1b, 1024 * 256 / 8);
  cvt_kernel<<<(512 * 1024 / 8 + 255) / 256, 256, 0, stream>>>(W2, W2b, 512 * 1024 / 8);
  cvt_kernel<<<(32 * 512 / 8 + 255) / 256, 256, 0, stream>>>(W3, W3b, 32 * 512 / 8);
  qb_kernel<<<16, 256, 0, stream>>>(W1, as1, ad1, Qb);

  // ---- CSR by dst (parallel scan) ----
  hipMemsetAsync(cnt, 0, (size_t)(Nn + 1) * 4, stream);
  int eb = (Etot + 255) / 256;
  hist_kernel<<<eb, 256, 0, stream>>>(edst, cnt, E, Nn);
  scan1_kernel<<<NB, 256, 0, stream>>>(cnt, bsum, Nn);
  scan2_kernel<<<1, 256, 0, stream>>>(bsum, boff, row_ptr, NB, Nn);
  scan3_kernel<<<NB, 256, 0, stream>>>(cnt, boff, row_ptr, cur, Nn);
  scatter_kernel<<<eb, 256, 0, stream>>>(esrc, edst, cur, src_sorted, E, Nn);

  // ---- layer 1 (input-space aggregation) ----
  gemm_mfma<128, 16, 4, 1, true><<<dim3(1, mb, 1), 256, 0, stream>>>(
      xb, Qb, sd1, nullptr, Nn, 16, 256, 256, 256, 16, 0, 0, 0, 0);
  aggx_kernel<<<(Nn + 3) / 4, 256, 0, stream>>>(row_ptr, src_sorted, sd1, xb, y, Nn);
  gemm_mfma<128, 128, 2, 2, false><<<dim3(2, mb, 4), 256, 0, stream>>>(
      y, W1b, z1, b1, Nn, 256, 256, 1024, 256, 1024, 256LL, 256LL * 256, 256LL, 256);
  ln1024_kernel<<<Nn, 256, 0, stream>>>(z1, g1, bb1, act1, Nn);

  // ---- layer 2 ----
  gemm_mfma<128, 128, 2, 2, false><<<dim3(4, mb, 1), 256, 0, stream>>>(
      act1, W2b, h2, nullptr, Nn, 512, 1024, 1024, 1024, 512, 0, 0, 0, 0);
  sd128_kernel<<<Nn, 256, 0, stream>>>(h2, as2, ad2, s2, d2, Nn);
  agg2m_kernel<<<(Nn + 3) / 4, 256, 0, stream>>>(row_ptr, src_sorted, s2, d2,
                                                 h2, b2, g2, bb2, act2, Nn);

  // ---- layer 3 ----
  gemm_mfma<128, 32, 4, 1, false><<<dim3(1, mb, 1), 256, 0, stream>>>(
      act2, W3b, h3, nullptr, Nn, 32, 512, 512, 512, 32, 0, 0, 0, 0);
  sd32_kernel<<<(Nn * 32 + 255) / 256, 256, 0, stream>>>(h3, as3, ad3, s3, d3, Nn);
  stats_kernel<<<(Nn + 255) / 256, 256, 0, stream>>>(row_ptr, src_sorted,
                                                     s3, d3, p3, invd3, Nn);
  final_kernel<<<(Nn * 32 + 255) / 256, 256, 0, stream>>>(row_ptr, src_sorted,
      p3, invd3, h3, b3, g3, bb3, out, Nn);
}